// Round 1
// baseline (671.364 us; speedup 1.0000x reference)
//
#include <hip/hip_runtime.h>

// SparseMoE encoder, fp32 baseline.
// Kernel 1: gate GEMM (patches @ w1 -> relu -> @ w2 -> top2 -> softmax) -> ws
// Kernel 2: per-patch block computes its 2 selected experts' conv stacks.

#define NPATCH 4096

// ---------------- gate kernel ----------------
// grid 256 blocks (16 patches each), 256 threads
__global__ __launch_bounds__(256) void gate_kernel(
    const float* __restrict__ x, const float* __restrict__ w1,
    const float* __restrict__ b1, const float* __restrict__ w2,
    const float* __restrict__ b2, int* __restrict__ gidx,
    float* __restrict__ gw)
{
  __shared__ float As[16][32];     // 16 patches x 32 k
  __shared__ float Bs[32][128];    // 32 k x 128 d
  __shared__ float hs[16][128];
  __shared__ float ls[16][8];

  const int t = threadIdx.x;
  const int p0 = blockIdx.x * 16;
  const int d  = t & 127;
  const int pr = (t >> 7) * 8;     // row offset 0 or 8

  float acc[8];
#pragma unroll
  for (int r = 0; r < 8; ++r) acc[r] = 0.f;

  for (int k0 = 0; k0 < 3072; k0 += 32) {
    const int c = k0 >> 10;           // channel
    const int i = (k0 >> 5) & 31;     // row within patch
    // A tile: 512 elems (one 32-wide row per patch)
    for (int idx = t; idx < 512; idx += 256) {
      int p = idx >> 5, j = idx & 31;
      int gp = p0 + p;
      int b = gp >> 8, ph = (gp >> 4) & 15, pw = gp & 15;
      As[p][j] = x[((size_t)(b * 3 + c) * 512 + ph * 32 + i) * 512 + pw * 32 + j];
    }
    // B tile: 1024 float4
#pragma unroll
    for (int r = 0; r < 4; ++r) {
      int fi = t + 256 * r;
      int kk = fi >> 5, dq = fi & 31;
      *(float4*)&Bs[kk][dq * 4] = *(const float4*)&w1[(size_t)(k0 + kk) * 128 + dq * 4];
    }
    __syncthreads();
    float cacc[8];
#pragma unroll
    for (int r = 0; r < 8; ++r) cacc[r] = 0.f;
#pragma unroll
    for (int kk = 0; kk < 32; ++kk) {
      float bv = Bs[kk][d];
#pragma unroll
      for (int r = 0; r < 8; ++r) cacc[r] = fmaf(As[pr + r][kk], bv, cacc[r]);
    }
#pragma unroll
    for (int r = 0; r < 8; ++r) acc[r] += cacc[r];
    __syncthreads();
  }
#pragma unroll
  for (int r = 0; r < 8; ++r)
    hs[pr + r][d] = fmaxf(acc[r] + b1[d], 0.f);
  __syncthreads();

  if (t < 128) {                       // (patch, expert) pairs
    int p = t >> 3, e = t & 7;
    float s = 0.f;
    for (int d0 = 0; d0 < 128; d0 += 32) {
      float cs = 0.f;
#pragma unroll
      for (int dd = 0; dd < 32; ++dd)
        cs = fmaf(hs[p][d0 + dd], w2[(d0 + dd) * 8 + e], cs);
      s += cs;
    }
    ls[p][e] = s + b2[e];
  }
  __syncthreads();

  if (t < 16) {
    int gp = p0 + t;
    float v[8];
#pragma unroll
    for (int e = 0; e < 8; ++e) v[e] = ls[t][e];
    int e0 = 0;
#pragma unroll
    for (int e = 1; e < 8; ++e) if (v[e] > v[e0]) e0 = e;
    int e1 = (e0 == 0) ? 1 : 0;
#pragma unroll
    for (int e = 0; e < 8; ++e) { if (e != e0 && v[e] > v[e1]) e1 = e; }
    float bexp = expf(v[e1] - v[e0]);    // v[e0] is the max
    float inv  = 1.f / (1.f + bexp);
    gidx[gp * 2 + 0] = e0;
    gidx[gp * 2 + 1] = e1;
    gw[gp * 2 + 0] = inv;
    gw[gp * 2 + 1] = bexp * inv;
  }
}

// ---------------- expert kernel ----------------
// grid 4096 blocks (one per patch), 256 threads
__global__ __launch_bounds__(256) void expert_kernel(
    const float* __restrict__ x,
    const float* __restrict__ dw1_w, const float* __restrict__ dw1_b,
    const float* __restrict__ pw1_w, const float* __restrict__ pw1_b,
    const float* __restrict__ dw2_w, const float* __restrict__ dw2_b,
    const float* __restrict__ pw2_w, const float* __restrict__ pw2_b,
    const int* __restrict__ gidx, const float* __restrict__ gw,
    float* __restrict__ out)
{
  __shared__ float ps[3][32][32];    // 12 KB patch
  __shared__ float y1s[3][256];      // 3 KB dw1 output [c][16*16]
  __shared__ float y3s[128][64];     // 32 KB dw2 output [d][8*8]

  const int t  = threadIdx.x;
  const int gp = blockIdx.x;
  const int b = gp >> 8, ph = (gp >> 4) & 15, pw = gp & 15;

  // patch -> LDS (coalesced 32-float rows)
  for (int i = t; i < 3072; i += 256) {
    int c = i >> 10, r = (i >> 5) & 31, j = i & 31;
    ps[c][r][j] = x[((size_t)(b * 3 + c) * 512 + ph * 32 + r) * 512 + pw * 32 + j];
  }

  const int d0   = (t >> 4) * 8;   // pw2: 8 output channels per thread
  const int s0   = (t & 15) * 4;   // pw2: 4 spatial positions per thread
  const int dd   = t >> 1;         // phase3: channel
  const int half = t & 1;          // phase3: which 4 output rows

  float out_acc[8];
#pragma unroll
  for (int i = 0; i < 8; ++i) out_acc[i] = 0.f;

  __syncthreads();

  for (int k = 0; k < 2; ++k) {
    const int   e  = gidx[gp * 2 + k];
    const float wk = gw[gp * 2 + k];

    // ---- dw1: [3,32,32] -> relu -> y1s [3,16,16] ----
    for (int oi = t; oi < 768; oi += 256) {
      int c = oi >> 8, p = (oi >> 4) & 15, q = oi & 15;
      float a = dw1_b[e * 3 + c];
      const float* wp_ = &dw1_w[(e * 3 + c) * 9];
#pragma unroll
      for (int di = 0; di < 3; ++di) {
        int ii = 2 * p + di - 1;
        if (ii < 0) continue;                 // max is 31, only low edge clips
#pragma unroll
        for (int dj = 0; dj < 3; ++dj) {
          int jj = 2 * q + dj - 1;
          if (jj < 0) continue;
          a = fmaf(wp_[di * 3 + dj], ps[c][ii][jj], a);
        }
      }
      y1s[c][p * 16 + q] = fmaxf(a, 0.f);
    }
    __syncthreads();

    // ---- fused pw1(3->128)+relu + dw2(3x3 s2 depthwise)+relu -> y3s ----
    {
      const float pwa = pw1_w[(e * 128 + dd) * 3 + 0];
      const float pwb = pw1_w[(e * 128 + dd) * 3 + 1];
      const float pwc = pw1_w[(e * 128 + dd) * 3 + 2];
      const float pb  = pw1_b[e * 128 + dd];
      float dwv[9];
#pragma unroll
      for (int i = 0; i < 9; ++i) dwv[i] = dw2_w[(e * 128 + dd) * 9 + i];
      const float db = dw2_b[e * 128 + dd];

      for (int u = half * 4; u < half * 4 + 4; ++u) {
        float vacc[8];
#pragma unroll
        for (int v = 0; v < 8; ++v) vacc[v] = db;
#pragma unroll
        for (int di = 0; di < 3; ++di) {
          int ii = 2 * u + di - 1;            // [-1, 15]
          if (ii < 0) continue;
          // build y2 row (16 cols) in registers from float4 LDS reads
          float y2row[16];
#pragma unroll
          for (int q4 = 0; q4 < 4; ++q4) {
            float4 a  = *(const float4*)&y1s[0][ii * 16 + q4 * 4];
            float4 bq = *(const float4*)&y1s[1][ii * 16 + q4 * 4];
            float4 cq = *(const float4*)&y1s[2][ii * 16 + q4 * 4];
            y2row[q4 * 4 + 0] = fmaxf(fmaf(pwa, a.x, fmaf(pwb, bq.x, fmaf(pwc, cq.x, pb))), 0.f);
            y2row[q4 * 4 + 1] = fmaxf(fmaf(pwa, a.y, fmaf(pwb, bq.y, fmaf(pwc, cq.y, pb))), 0.f);
            y2row[q4 * 4 + 2] = fmaxf(fmaf(pwa, a.z, fmaf(pwb, bq.z, fmaf(pwc, cq.z, pb))), 0.f);
            y2row[q4 * 4 + 3] = fmaxf(fmaf(pwa, a.w, fmaf(pwb, bq.w, fmaf(pwc, cq.w, pb))), 0.f);
          }
#pragma unroll
          for (int v = 0; v < 8; ++v) {
#pragma unroll
            for (int dj = 0; dj < 3; ++dj) {
              int jj = 2 * v + dj - 1;        // [-1, 15]
              if (jj < 0) continue;
              vacc[v] = fmaf(dwv[di * 3 + dj], y2row[jj], vacc[v]);
            }
          }
        }
#pragma unroll
        for (int v = 0; v < 8; ++v)
          y3s[dd][u * 8 + v] = fmaxf(vacc[v], 0.f);
      }
    }
    __syncthreads();

    // ---- pw2: 128x128 over 64 positions, register-blocked 8d x 4s ----
    {
      float acc2[8][4];
#pragma unroll
      for (int i = 0; i < 8; ++i)
#pragma unroll
        for (int j = 0; j < 4; ++j) acc2[i][j] = 0.f;

      for (int c0 = 0; c0 < 128; c0 += 4) {
        float4 wr[8];
#pragma unroll
        for (int i = 0; i < 8; ++i)
          wr[i] = *(const float4*)&pw2_w[(size_t)(e * 128 + d0 + i) * 128 + c0];
#pragma unroll
        for (int cc = 0; cc < 4; ++cc) {
          float4 y4 = *(const float4*)&y3s[c0 + cc][s0];
#pragma unroll
          for (int i = 0; i < 8; ++i) {
            float wv = (cc == 0) ? wr[i].x : (cc == 1) ? wr[i].y : (cc == 2) ? wr[i].z : wr[i].w;
            acc2[i][0] = fmaf(wv, y4.x, acc2[i][0]);
            acc2[i][1] = fmaf(wv, y4.y, acc2[i][1]);
            acc2[i][2] = fmaf(wv, y4.z, acc2[i][2]);
            acc2[i][3] = fmaf(wv, y4.w, acc2[i][3]);
          }
        }
      }
      // bias + relu per position, sum 4 local positions, reduce 16 lanes
#pragma unroll
      for (int i = 0; i < 8; ++i) {
        float bb = pw2_b[e * 128 + d0 + i];
        float s = fmaxf(acc2[i][0] + bb, 0.f) + fmaxf(acc2[i][1] + bb, 0.f)
                + fmaxf(acc2[i][2] + bb, 0.f) + fmaxf(acc2[i][3] + bb, 0.f);
        s += __shfl_xor(s, 1);
        s += __shfl_xor(s, 2);
        s += __shfl_xor(s, 4);
        s += __shfl_xor(s, 8);
        out_acc[i] = fmaf(wk * 0.015625f, s, out_acc[i]);   // mean /64, weighted
      }
    }
    __syncthreads();
  }

  if ((t & 15) == 0) {
#pragma unroll
    for (int i = 0; i < 8; ++i)
      out[((size_t)(b * 128 + d0 + i) * 16 + ph) * 16 + pw] = out_acc[i];
  }
}

extern "C" void kernel_launch(void* const* d_in, const int* in_sizes, int n_in,
                              void* d_out, int out_size, void* d_ws, size_t ws_size,
                              hipStream_t stream) {
  const float* x       = (const float*)d_in[0];
  const float* gate_w1 = (const float*)d_in[1];
  const float* gate_b1 = (const float*)d_in[2];
  const float* gate_w2 = (const float*)d_in[3];
  const float* gate_b2 = (const float*)d_in[4];
  const float* dw1_w   = (const float*)d_in[5];
  const float* dw1_b   = (const float*)d_in[6];
  const float* pw1_w   = (const float*)d_in[7];
  const float* pw1_b   = (const float*)d_in[8];
  const float* dw2_w   = (const float*)d_in[9];
  const float* dw2_b   = (const float*)d_in[10];
  const float* pw2_w   = (const float*)d_in[11];
  const float* pw2_b   = (const float*)d_in[12];
  float* out = (float*)d_out;

  int*   gidx = (int*)d_ws;
  float* gw   = (float*)((char*)d_ws + (size_t)NPATCH * 2 * sizeof(int));

  gate_kernel<<<NPATCH / 16, 256, 0, stream>>>(x, gate_w1, gate_b1, gate_w2, gate_b2, gidx, gw);
  expert_kernel<<<NPATCH, 256, 0, stream>>>(x, dw1_w, dw1_b, pw1_w, pw1_b,
                                            dw2_w, dw2_b, pw2_w, pw2_b, gidx, gw, out);
}

// Round 4
// 477.914 us; speedup vs baseline: 1.4048x; 1.4048x over previous
//
#include <hip/hip_runtime.h>

#define NPATCH 4096

typedef __attribute__((ext_vector_type(8))) __bf16 bf16x8;
typedef __attribute__((ext_vector_type(4))) __bf16 bf16x4;
typedef __attribute__((ext_vector_type(4))) float f32x4;

// ---------------- gate kernel ----------------
// 256 blocks x 256 threads; block = 16 patches x 128 d; thread = 4p x 2d.
// A (patches) read straight from global (wave-uniform addrs -> L1 broadcast);
// only w1 staged in LDS.
__global__ __launch_bounds__(256) void gate_kernel(
    const float* __restrict__ x, const float* __restrict__ w1,
    const float* __restrict__ b1, const float* __restrict__ w2,
    const float* __restrict__ b2, int* __restrict__ gidx,
    float* __restrict__ gw)
{
  __shared__ float Bs[32][128];
  __shared__ float hs[16][128];
  __shared__ float ls[16][8];

  const int t  = threadIdx.x;
  const int p0 = blockIdx.x * 16;
  const int dp = t & 63;       // d-pair: d = 2*dp, 2*dp+1
  const int pg = t >> 6;       // patch group: patches pg*4 .. pg*4+3

  size_t pbase[4];
#pragma unroll
  for (int pp = 0; pp < 4; ++pp) {
    int gp = p0 + pg * 4 + pp;
    int b = gp >> 8, ph = (gp >> 4) & 15, pwc = gp & 15;
    pbase[pp] = ((size_t)(b * 3) * 512 + ph * 32) * 512 + pwc * 32;
  }

  float acc[4][2];
#pragma unroll
  for (int pp = 0; pp < 4; ++pp) { acc[pp][0] = 0.f; acc[pp][1] = 0.f; }

  for (int k0 = 0; k0 < 3072; k0 += 32) {
    // stage w1 tile [32k][128d]
#pragma unroll
    for (int r = 0; r < 4; ++r) {
      int fi = t + 256 * r;
      int kk = fi >> 5, dq = fi & 31;
      *(float4*)&Bs[kk][dq * 4] = *(const float4*)&w1[(size_t)(k0 + kk) * 128 + dq * 4];
    }
    __syncthreads();

    // this k-tile = one 32-float row of one channel of the patch
    const size_t off = ((size_t)(k0 >> 10)) * 262144 + (size_t)((k0 >> 5) & 31) * 512;

    float cacc[4][2];
#pragma unroll
    for (int pp = 0; pp < 4; ++pp) { cacc[pp][0] = 0.f; cacc[pp][1] = 0.f; }

#pragma unroll
    for (int kq = 0; kq < 8; ++kq) {
      float4 av[4];
#pragma unroll
      for (int pp = 0; pp < 4; ++pp)
        av[pp] = *(const float4*)&x[pbase[pp] + off + kq * 4];
#pragma unroll
      for (int kk = 0; kk < 4; ++kk) {
        float2 bv = *(const float2*)&Bs[kq * 4 + kk][dp * 2];
#pragma unroll
        for (int pp = 0; pp < 4; ++pp) {
          float a = (kk == 0) ? av[pp].x : (kk == 1) ? av[pp].y : (kk == 2) ? av[pp].z : av[pp].w;
          cacc[pp][0] = fmaf(a, bv.x, cacc[pp][0]);
          cacc[pp][1] = fmaf(a, bv.y, cacc[pp][1]);
        }
      }
    }
#pragma unroll
    for (int pp = 0; pp < 4; ++pp) {   // per-32 chunk accumulate (matches r1 numerics)
      acc[pp][0] += cacc[pp][0];
      acc[pp][1] += cacc[pp][1];
    }
    __syncthreads();
  }

#pragma unroll
  for (int pp = 0; pp < 4; ++pp) {
    hs[pg * 4 + pp][dp * 2 + 0] = fmaxf(acc[pp][0] + b1[dp * 2 + 0], 0.f);
    hs[pg * 4 + pp][dp * 2 + 1] = fmaxf(acc[pp][1] + b1[dp * 2 + 1], 0.f);
  }
  __syncthreads();

  if (t < 128) {                       // (patch, expert) pairs
    int p = t >> 3, e = t & 7;
    float s = 0.f;
    for (int d0 = 0; d0 < 128; d0 += 32) {
      float cs = 0.f;
#pragma unroll
      for (int dd = 0; dd < 32; ++dd)
        cs = fmaf(hs[p][d0 + dd], w2[(d0 + dd) * 8 + e], cs);
      s += cs;
    }
    ls[p][e] = s + b2[e];
  }
  __syncthreads();

  if (t < 16) {
    int gp = p0 + t;
    float v[8];
#pragma unroll
    for (int e = 0; e < 8; ++e) v[e] = ls[t][e];
    int e0 = 0;
#pragma unroll
    for (int e = 1; e < 8; ++e) if (v[e] > v[e0]) e0 = e;
    int e1 = (e0 == 0) ? 1 : 0;
#pragma unroll
    for (int e = 0; e < 8; ++e) { if (e != e0 && v[e] > v[e1]) e1 = e; }
    float bexp = expf(v[e1] - v[e0]);
    float inv  = 1.f / (1.f + bexp);
    gidx[gp * 2 + 0] = e0;
    gidx[gp * 2 + 1] = e1;
    gw[gp * 2 + 0] = inv;
    gw[gp * 2 + 1] = bexp * inv;
  }
}

// ---------------- expert kernel ----------------
// 4096 blocks (one per patch), 256 threads. pw2 on bf16 MFMA.
__global__ __launch_bounds__(256) void expert_kernel(
    const float* __restrict__ x,
    const float* __restrict__ dw1_w, const float* __restrict__ dw1_b,
    const float* __restrict__ pw1_w, const float* __restrict__ pw1_b,
    const float* __restrict__ dw2_w, const float* __restrict__ dw2_b,
    const float* __restrict__ pw2_w, const float* __restrict__ pw2_b,
    const int* __restrict__ gidx, const float* __restrict__ gw,
    float* __restrict__ out)
{
  __shared__ float  ps[3][32][32];     // 12 KB patch
  __shared__ float  y1s[3][256];       // 3 KB
  __shared__ __bf16 y3b[64][136];      // 17 KB  [pos][ch], pad 8
  __shared__ __bf16 wlds[128][136];    // 34 KB  [out_ch][in_ch], pad 8
  __shared__ float  posum[4][128];
  __shared__ float  outbuf[128];

  const int t  = threadIdx.x;
  const int gp = blockIdx.x;
  const int b = gp >> 8, ph = (gp >> 4) & 15, pw = gp & 15;
  const int l = t & 63, wv = t >> 6;

  for (int i = t; i < 3072; i += 256) {
    int c = i >> 10, r = (i >> 5) & 31, j = i & 31;
    ps[c][r][j] = x[((size_t)(b * 3 + c) * 512 + ph * 32 + r) * 512 + pw * 32 + j];
  }
  if (t < 128) outbuf[t] = 0.f;

  const int dd   = t >> 1;   // phase3 channel
  const int half = t & 1;

  __syncthreads();

  for (int k = 0; k < 2; ++k) {
    const int   e  = gidx[gp * 2 + k];
    const float wk = gw[gp * 2 + k];

    // ---- dw1: [3,32,32] -> relu -> y1s [3,16,16] ----
    for (int oi = t; oi < 768; oi += 256) {
      int c = oi >> 8, p = (oi >> 4) & 15, q = oi & 15;
      float a = dw1_b[e * 3 + c];
      const float* wp_ = &dw1_w[(e * 3 + c) * 9];
#pragma unroll
      for (int di = 0; di < 3; ++di) {
        int ii = 2 * p + di - 1;
        if (ii < 0) continue;
#pragma unroll
        for (int dj = 0; dj < 3; ++dj) {
          int jj = 2 * q + dj - 1;
          if (jj < 0) continue;
          a = fmaf(wp_[di * 3 + dj], ps[c][ii][jj], a);
        }
      }
      y1s[c][p * 16 + q] = fmaxf(a, 0.f);
    }
    // ---- pw2 weights -> bf16 LDS [n][k] ----
    for (int i4 = t; i4 < 4096; i4 += 256) {
      int n = i4 >> 5, kq = i4 & 31;
      float4 w4 = *(const float4*)&pw2_w[((size_t)(e * 128 + n)) * 128 + kq * 4];
      bf16x4 pk = { (__bf16)w4.x, (__bf16)w4.y, (__bf16)w4.z, (__bf16)w4.w };
      *(bf16x4*)&wlds[n][kq * 4] = pk;
    }
    __syncthreads();

    // ---- fused pw1(3->128)+relu + dw2(3x3 s2 dw)+relu -> y3b[s][dd] ----
    {
      const float pwa = pw1_w[(e * 128 + dd) * 3 + 0];
      const float pwb = pw1_w[(e * 128 + dd) * 3 + 1];
      const float pwc = pw1_w[(e * 128 + dd) * 3 + 2];
      const float pb  = pw1_b[e * 128 + dd];
      float dwv[9];
#pragma unroll
      for (int i = 0; i < 9; ++i) dwv[i] = dw2_w[(e * 128 + dd) * 9 + i];
      const float db = dw2_b[e * 128 + dd];

      for (int u = half * 4; u < half * 4 + 4; ++u) {
        float vacc[8];
#pragma unroll
        for (int v = 0; v < 8; ++v) vacc[v] = db;
#pragma unroll
        for (int di = 0; di < 3; ++di) {
          int ii = 2 * u + di - 1;
          if (ii < 0) continue;
          float y2row[16];
#pragma unroll
          for (int q4 = 0; q4 < 4; ++q4) {
            float4 a  = *(const float4*)&y1s[0][ii * 16 + q4 * 4];
            float4 bq = *(const float4*)&y1s[1][ii * 16 + q4 * 4];
            float4 cq = *(const float4*)&y1s[2][ii * 16 + q4 * 4];
            y2row[q4 * 4 + 0] = fmaxf(fmaf(pwa, a.x, fmaf(pwb, bq.x, fmaf(pwc, cq.x, pb))), 0.f);
            y2row[q4 * 4 + 1] = fmaxf(fmaf(pwa, a.y, fmaf(pwb, bq.y, fmaf(pwc, cq.y, pb))), 0.f);
            y2row[q4 * 4 + 2] = fmaxf(fmaf(pwa, a.z, fmaf(pwb, bq.z, fmaf(pwc, cq.z, pb))), 0.f);
            y2row[q4 * 4 + 3] = fmaxf(fmaf(pwa, a.w, fmaf(pwb, bq.w, fmaf(pwc, cq.w, pb))), 0.f);
          }
#pragma unroll
          for (int v = 0; v < 8; ++v) {
#pragma unroll
            for (int dj = 0; dj < 3; ++dj) {
              int jj = 2 * v + dj - 1;
              if (jj < 0) continue;
              vacc[v] = fmaf(dwv[di * 3 + dj], y2row[jj], vacc[v]);
            }
          }
        }
#pragma unroll
        for (int v = 0; v < 8; ++v)
          y3b[u * 8 + v][dd] = (__bf16)fmaxf(vacc[v], 0.f);
      }
    }
    __syncthreads();

    // ---- pw2 via MFMA: [64 pos] x [128 in] x [128 out] ----
    {
      f32x4 acc[8];
#pragma unroll
      for (int nt = 0; nt < 8; ++nt) acc[nt] = (f32x4){0.f, 0.f, 0.f, 0.f};

      const int row  = wv * 16 + (l & 15);
      const int kofs = (l >> 4) * 8;
      bf16x8 afrag[4];
#pragma unroll
      for (int kt = 0; kt < 4; ++kt)
        afrag[kt] = *(const bf16x8*)&y3b[row][kt * 32 + kofs];

#pragma unroll
      for (int kt = 0; kt < 4; ++kt) {
#pragma unroll
        for (int nt = 0; nt < 8; ++nt) {
          bf16x8 bfrag = *(const bf16x8*)&wlds[nt * 16 + (l & 15)][kt * 32 + kofs];
          acc[nt] = __builtin_amdgcn_mfma_f32_16x16x32_bf16(afrag[kt], bfrag, acc[nt], 0, 0, 0);
        }
      }
      // bias+relu per position, sum 4 rows, reduce across row-groups
#pragma unroll
      for (int nt = 0; nt < 8; ++nt) {
        float bias = pw2_b[e * 128 + nt * 16 + (l & 15)];
        float s = fmaxf(acc[nt][0] + bias, 0.f) + fmaxf(acc[nt][1] + bias, 0.f)
                + fmaxf(acc[nt][2] + bias, 0.f) + fmaxf(acc[nt][3] + bias, 0.f);
        s += __shfl_xor(s, 16);
        s += __shfl_xor(s, 32);
        if (l < 16) posum[wv][nt * 16 + l] = s;
      }
    }
    __syncthreads();

    if (t < 128)
      outbuf[t] += wk * 0.015625f *
                   (posum[0][t] + posum[1][t] + posum[2][t] + posum[3][t]);
    __syncthreads();
  }

  if (t < 128)
    out[((size_t)(b * 128 + t) * 16 + ph) * 16 + pw] = outbuf[t];
}

extern "C" void kernel_launch(void* const* d_in, const int* in_sizes, int n_in,
                              void* d_out, int out_size, void* d_ws, size_t ws_size,
                              hipStream_t stream) {
  const float* x       = (const float*)d_in[0];
  const float* gate_w1 = (const float*)d_in[1];
  const float* gate_b1 = (const float*)d_in[2];
  const float* gate_w2 = (const float*)d_in[3];
  const float* gate_b2 = (const float*)d_in[4];
  const float* dw1_w   = (const float*)d_in[5];
  const float* dw1_b   = (const float*)d_in[6];
  const float* pw1_w   = (const float*)d_in[7];
  const float* pw1_b   = (const float*)d_in[8];
  const float* dw2_w   = (const float*)d_in[9];
  const float* dw2_b   = (const float*)d_in[10];
  const float* pw2_w   = (const float*)d_in[11];
  const float* pw2_b   = (const float*)d_in[12];
  float* out = (float*)d_out;

  int*   gidx = (int*)d_ws;
  float* gw   = (float*)((char*)d_ws + (size_t)NPATCH * 2 * sizeof(int));

  gate_kernel<<<NPATCH / 16, 256, 0, stream>>>(x, gate_w1, gate_b1, gate_w2, gate_b2, gidx, gw);
  expert_kernel<<<NPATCH, 256, 0, stream>>>(x, dw1_w, dw1_b, pw1_w, pw1_b,
                                            dw2_w, dw2_b, pw2_w, pw2_b, gidx, gw, out);
}

// Round 6
// 468.369 us; speedup vs baseline: 1.4334x; 1.0204x over previous
//
#include <hip/hip_runtime.h>

#define NPATCH 4096

typedef __attribute__((ext_vector_type(8))) __bf16 bf16x8;
typedef __attribute__((ext_vector_type(4))) __bf16 bf16x4;
typedef __attribute__((ext_vector_type(4))) float f32x4;

__device__ inline void gload_lds16(const float* g, float* l) {
  __builtin_amdgcn_global_load_lds((const __attribute__((address_space(1))) void*)g,
                                   (__attribute__((address_space(3))) void*)l, 16, 0, 0);
}

// ---------------- prep kernel: pack pw2 weights bf16 in MFMA fragment order ----------------
// wpk[(((e*4+kt)*8+nt)*64 + l)] = 8 bf16 = pw2_w[e][nt*16+(l&15)][kt*32+(l>>4)*8 .. +8]
__global__ __launch_bounds__(256) void prep_kernel(const float* __restrict__ pw2_w,
                                                   bf16x8* __restrict__ wpk) {
  int tid = blockIdx.x * 256 + threadIdx.x;    // 64 blocks -> 16384 threads
  int l = tid & 63, nt = (tid >> 6) & 7, kt = (tid >> 9) & 3, e = tid >> 11;
  int n = nt * 16 + (l & 15);
  int k = kt * 32 + (l >> 4) * 8;
  const float* src = &pw2_w[((size_t)(e * 128 + n)) * 128 + k];
  float4 a = *(const float4*)src;
  float4 b = *(const float4*)(src + 4);
  bf16x8 r = { (__bf16)a.x, (__bf16)a.y, (__bf16)a.z, (__bf16)a.w,
               (__bf16)b.x, (__bf16)b.y, (__bf16)b.z, (__bf16)b.w };
  wpk[tid] = r;    // tid == ((e*4+kt)*8+nt)*64 + l
}

// ---------------- gate kernel ----------------
// 512 blocks x 256 threads; block = 8 patches x 128 d; thread = 4 patches x 1 d.
// w1 tile double-buffered in LDS via global_load_lds (issue-early); x read as
// wave-uniform float4 broadcasts. Per-output FMA order identical to passing r4.
__global__ __launch_bounds__(256) void gate_kernel(
    const float* __restrict__ x, const float* __restrict__ w1,
    const float* __restrict__ b1, const float* __restrict__ w2,
    const float* __restrict__ b2, int* __restrict__ gidx,
    float* __restrict__ gw)
{
  __shared__ float Bs[2][32][128];   // 32 KB double buffer
  __shared__ float hs[8][128];
  __shared__ float ls[8][8];

  const int t  = threadIdx.x;
  const int p0 = blockIdx.x * 8;
  const int d  = t & 127;
  const int pg = t >> 7;            // 0/1, uniform per wave
  const int wv = t >> 6, l = t & 63;

  size_t pbase[4];
#pragma unroll
  for (int pp = 0; pp < 4; ++pp) {
    int gp = p0 + pg * 4 + pp;
    int b = gp >> 8, ph = (gp >> 4) & 15, pwc = gp & 15;
    pbase[pp] = ((size_t)(b * 3) * 512 + ph * 32) * 512 + pwc * 32;
  }

  float acc[4] = {0.f, 0.f, 0.f, 0.f};

  // prologue: stage tile 0 into buf 0
  {
    const float* g  = w1 + wv * 1024 + l * 4;
    float*       ld = &Bs[0][0][0] + wv * 1024 + l * 4;
#pragma unroll
    for (int i = 0; i < 4; ++i) gload_lds16(g + i * 256, ld + i * 256);
  }
  asm volatile("s_waitcnt vmcnt(0)" ::: "memory");
  __syncthreads();

  for (int kt = 0; kt < 96; ++kt) {
    const int cur = kt & 1;
    const int k0  = kt * 32;
    // issue next tile's staging first (latency hides under compute)
    if (kt + 1 < 96) {
      const float* g  = w1 + (size_t)(k0 + 32) * 128 + wv * 1024 + l * 4;
      float*       ld = &Bs[cur ^ 1][0][0] + wv * 1024 + l * 4;
#pragma unroll
      for (int i = 0; i < 4; ++i) gload_lds16(g + i * 256, ld + i * 256);
    }

    // this k-tile = one 32-float row of one channel of the patch
    const size_t off = ((size_t)(k0 >> 10)) * 262144 + (size_t)((k0 >> 5) & 31) * 512;

    float cacc[4] = {0.f, 0.f, 0.f, 0.f};
#pragma unroll
    for (int kq = 0; kq < 8; ++kq) {
      float4 av[4];
#pragma unroll
      for (int pp = 0; pp < 4; ++pp)
        av[pp] = *(const float4*)&x[pbase[pp] + off + kq * 4];
#pragma unroll
      for (int kk = 0; kk < 4; ++kk) {
        float bv = Bs[cur][kq * 4 + kk][d];
#pragma unroll
        for (int pp = 0; pp < 4; ++pp) {
          float a = (kk == 0) ? av[pp].x : (kk == 1) ? av[pp].y : (kk == 2) ? av[pp].z : av[pp].w;
          cacc[pp] = fmaf(a, bv, cacc[pp]);
        }
      }
    }
#pragma unroll
    for (int pp = 0; pp < 4; ++pp) acc[pp] += cacc[pp];   // per-32 chunk accumulate

    asm volatile("s_waitcnt vmcnt(0)" ::: "memory");
    __syncthreads();
  }

#pragma unroll
  for (int pp = 0; pp < 4; ++pp)
    hs[pg * 4 + pp][d] = fmaxf(acc[pp] + b1[d], 0.f);
  __syncthreads();

  if (t < 64) {                       // (patch, expert) pairs
    int p = t >> 3, e = t & 7;
    float s = 0.f;
    for (int d0 = 0; d0 < 128; d0 += 32) {
      float cs = 0.f;
#pragma unroll
      for (int dd = 0; dd < 32; ++dd)
        cs = fmaf(hs[p][d0 + dd], w2[(d0 + dd) * 8 + e], cs);
      s += cs;
    }
    ls[p][e] = s + b2[e];
  }
  __syncthreads();

  if (t < 8) {
    int gp = p0 + t;
    float v[8];
#pragma unroll
    for (int e = 0; e < 8; ++e) v[e] = ls[t][e];
    int e0 = 0;
#pragma unroll
    for (int e = 1; e < 8; ++e) if (v[e] > v[e0]) e0 = e;
    int e1 = (e0 == 0) ? 1 : 0;
#pragma unroll
    for (int e = 0; e < 8; ++e) { if (e != e0 && v[e] > v[e1]) e1 = e; }
    float bexp = expf(v[e1] - v[e0]);
    float inv  = 1.f / (1.f + bexp);
    gidx[gp * 2 + 0] = e0;
    gidx[gp * 2 + 1] = e1;
    gw[gp * 2 + 0] = inv;
    gw[gp * 2 + 1] = bexp * inv;
  }
}

// ---------------- expert kernel ----------------
// 4096 blocks (one per patch), 256 threads. pw2 on bf16 MFMA.
// PACKED: B-fragments from prepacked global (L2-resident), no weight LDS.
// !PACKED (ws too small): round-4 proven path, weights staged to LDS per expert.
template<bool PACKED>
__global__ __launch_bounds__(256) void expert_kernel(
    const float* __restrict__ x,
    const float* __restrict__ dw1_w, const float* __restrict__ dw1_b,
    const float* __restrict__ pw1_w, const float* __restrict__ pw1_b,
    const float* __restrict__ dw2_w, const float* __restrict__ dw2_b,
    const bf16x8* __restrict__ wpk, const float* __restrict__ pw2_w,
    const float* __restrict__ pw2_b,
    const int* __restrict__ gidx, const float* __restrict__ gw,
    float* __restrict__ out)
{
  __shared__ float  ps[3][32][36];     // 13.5 KB patch (pad 36: 16B-aligned rows, bank-spread)
  __shared__ float  y1s[3][256];       // 3 KB
  __shared__ __bf16 y3b[64][136];      // 17 KB  [pos][ch], pad 8
  __shared__ float  posum[4][128];
  __shared__ float  outbuf[128];

  const int t  = threadIdx.x;
  const int gp = blockIdx.x;
  const int b = gp >> 8, ph = (gp >> 4) & 15, pw = gp & 15;
  const int l = t & 63, wv = t >> 6;

  // patch -> LDS, float4 (768 f4, 3 per thread)
#pragma unroll
  for (int it = 0; it < 3; ++it) {
    int f4i = t + 256 * it;
    int c = f4i >> 8, r = (f4i >> 3) & 31, j4 = f4i & 7;
    *(float4*)&ps[c][r][j4 * 4] =
        *(const float4*)&x[((size_t)(b * 3 + c) * 512 + ph * 32 + r) * 512 + pw * 32 + j4 * 4];
  }
  if (t < 128) outbuf[t] = 0.f;

  const int dd   = t >> 1;   // fused-phase channel
  const int half = t & 1;

  __syncthreads();

  for (int k = 0; k < 2; ++k) {
    const int   e  = gidx[gp * 2 + k];
    const float wk = gw[gp * 2 + k];

    // ---- dw1: [3,32,32] -> relu -> y1s [3,16,16] ----
    for (int oi = t; oi < 768; oi += 256) {
      int c = oi >> 8, p = (oi >> 4) & 15, q = oi & 15;
      float a = dw1_b[e * 3 + c];
      const float* wp_ = &dw1_w[(e * 3 + c) * 9];
#pragma unroll
      for (int di = 0; di < 3; ++di) {
        int ii = 2 * p + di - 1;
        if (ii < 0) continue;
#pragma unroll
        for (int dj = 0; dj < 3; ++dj) {
          int jj = 2 * q + dj - 1;
          if (jj < 0) continue;
          a = fmaf(wp_[di * 3 + dj], ps[c][ii][jj], a);
        }
      }
      y1s[c][p * 16 + q] = fmaxf(a, 0.f);
    }
    __syncthreads();

    // ---- fused pw1(3->128)+relu + dw2(3x3 s2 dw)+relu -> y3b[s][dd] ----
    {
      const float pwa = pw1_w[(e * 128 + dd) * 3 + 0];
      const float pwb = pw1_w[(e * 128 + dd) * 3 + 1];
      const float pwc = pw1_w[(e * 128 + dd) * 3 + 2];
      const float pb  = pw1_b[e * 128 + dd];
      float dwv[9];
#pragma unroll
      for (int i = 0; i < 9; ++i) dwv[i] = dw2_w[(e * 128 + dd) * 9 + i];
      const float db = dw2_b[e * 128 + dd];

      for (int u = half * 4; u < half * 4 + 4; ++u) {
        float vacc[8];
#pragma unroll
        for (int v = 0; v < 8; ++v) vacc[v] = db;
#pragma unroll
        for (int di = 0; di < 3; ++di) {
          int ii = 2 * u + di - 1;
          if (ii < 0) continue;
          float y2row[16];
#pragma unroll
          for (int q4 = 0; q4 < 4; ++q4) {
            float4 a  = *(const float4*)&y1s[0][ii * 16 + q4 * 4];
            float4 bq = *(const float4*)&y1s[1][ii * 16 + q4 * 4];
            float4 cq = *(const float4*)&y1s[2][ii * 16 + q4 * 4];
            y2row[q4 * 4 + 0] = fmaxf(fmaf(pwa, a.x, fmaf(pwb, bq.x, fmaf(pwc, cq.x, pb))), 0.f);
            y2row[q4 * 4 + 1] = fmaxf(fmaf(pwa, a.y, fmaf(pwb, bq.y, fmaf(pwc, cq.y, pb))), 0.f);
            y2row[q4 * 4 + 2] = fmaxf(fmaf(pwa, a.z, fmaf(pwb, bq.z, fmaf(pwc, cq.z, pb))), 0.f);
            y2row[q4 * 4 + 3] = fmaxf(fmaf(pwa, a.w, fmaf(pwb, bq.w, fmaf(pwc, cq.w, pb))), 0.f);
          }
#pragma unroll
          for (int v = 0; v < 8; ++v) {
#pragma unroll
            for (int dj = 0; dj < 3; ++dj) {
              int jj = 2 * v + dj - 1;
              if (jj < 0) continue;
              vacc[v] = fmaf(dwv[di * 3 + dj], y2row[jj], vacc[v]);
            }
          }
        }
#pragma unroll
        for (int v = 0; v < 8; ++v)
          y3b[u * 8 + v][dd] = (__bf16)fmaxf(vacc[v], 0.f);
      }
    }

    if constexpr (PACKED) {
      __syncthreads();
      // ---- pw2 via MFMA: B-fragments straight from prepacked global ----
      f32x4 acc[8];
#pragma unroll
      for (int nt = 0; nt < 8; ++nt) acc[nt] = (f32x4){0.f, 0.f, 0.f, 0.f};

      const int row  = wv * 16 + (l & 15);
      const int kofs = (l >> 4) * 8;
      bf16x8 afrag[4];
#pragma unroll
      for (int kt = 0; kt < 4; ++kt)
        afrag[kt] = *(const bf16x8*)&y3b[row][kt * 32 + kofs];

      const bf16x8* wb = wpk + (size_t)e * 2048 + l;
#pragma unroll
      for (int kt = 0; kt < 4; ++kt) {
        bf16x8 bf[8];
#pragma unroll
        for (int nt = 0; nt < 8; ++nt) bf[nt] = wb[(kt * 8 + nt) * 64];
#pragma unroll
        for (int nt = 0; nt < 8; ++nt)
          acc[nt] = __builtin_amdgcn_mfma_f32_16x16x32_bf16(afrag[kt], bf[nt], acc[nt], 0, 0, 0);
      }
#pragma unroll
      for (int nt = 0; nt < 8; ++nt) {
        float bias = pw2_b[e * 128 + nt * 16 + (l & 15)];
        float s = fmaxf(acc[nt][0] + bias, 0.f) + fmaxf(acc[nt][1] + bias, 0.f)
                + fmaxf(acc[nt][2] + bias, 0.f) + fmaxf(acc[nt][3] + bias, 0.f);
        s += __shfl_xor(s, 16);
        s += __shfl_xor(s, 32);
        if (l < 16) posum[wv][nt * 16 + l] = s;
      }
    } else {
      // ---- round-4 fallback: stage bf16 weights to LDS, then MFMA ----
      __shared__ __bf16 wlds[128][136];   // 34 KB
      for (int i4 = t; i4 < 4096; i4 += 256) {
        int n = i4 >> 5, kq = i4 & 31;
        float4 w4 = *(const float4*)&pw2_w[((size_t)(e * 128 + n)) * 128 + kq * 4];
        bf16x4 pk = { (__bf16)w4.x, (__bf16)w4.y, (__bf16)w4.z, (__bf16)w4.w };
        *(bf16x4*)&wlds[n][kq * 4] = pk;
      }
      __syncthreads();

      f32x4 acc[8];
#pragma unroll
      for (int nt = 0; nt < 8; ++nt) acc[nt] = (f32x4){0.f, 0.f, 0.f, 0.f};

      const int row  = wv * 16 + (l & 15);
      const int kofs = (l >> 4) * 8;
      bf16x8 afrag[4];
#pragma unroll
      for (int kt = 0; kt < 4; ++kt)
        afrag[kt] = *(const bf16x8*)&y3b[row][kt * 32 + kofs];

#pragma unroll
      for (int kt = 0; kt < 4; ++kt) {
#pragma unroll
        for (int nt = 0; nt < 8; ++nt) {
          bf16x8 bfrag = *(const bf16x8*)&wlds[nt * 16 + (l & 15)][kt * 32 + kofs];
          acc[nt] = __builtin_amdgcn_mfma_f32_16x16x32_bf16(afrag[kt], bfrag, acc[nt], 0, 0, 0);
        }
      }
#pragma unroll
      for (int nt = 0; nt < 8; ++nt) {
        float bias = pw2_b[e * 128 + nt * 16 + (l & 15)];
        float s = fmaxf(acc[nt][0] + bias, 0.f) + fmaxf(acc[nt][1] + bias, 0.f)
                + fmaxf(acc[nt][2] + bias, 0.f) + fmaxf(acc[nt][3] + bias, 0.f);
        s += __shfl_xor(s, 16);
        s += __shfl_xor(s, 32);
        if (l < 16) posum[wv][nt * 16 + l] = s;
      }
    }
    __syncthreads();

    if (t < 128)
      outbuf[t] += wk * 0.015625f *
                   (posum[0][t] + posum[1][t] + posum[2][t] + posum[3][t]);
    __syncthreads();
  }

  if (t < 128)
    out[((size_t)(b * 128 + t) * 16 + ph) * 16 + pw] = outbuf[t];
}

extern "C" void kernel_launch(void* const* d_in, const int* in_sizes, int n_in,
                              void* d_out, int out_size, void* d_ws, size_t ws_size,
                              hipStream_t stream) {
  const float* x       = (const float*)d_in[0];
  const float* gate_w1 = (const float*)d_in[1];
  const float* gate_b1 = (const float*)d_in[2];
  const float* gate_w2 = (const float*)d_in[3];
  const float* gate_b2 = (const float*)d_in[4];
  const float* dw1_w   = (const float*)d_in[5];
  const float* dw1_b   = (const float*)d_in[6];
  const float* pw1_w   = (const float*)d_in[7];
  const float* pw1_b   = (const float*)d_in[8];
  const float* dw2_w   = (const float*)d_in[9];
  const float* dw2_b   = (const float*)d_in[10];
  const float* pw2_w   = (const float*)d_in[11];
  const float* pw2_b   = (const float*)d_in[12];
  float* out = (float*)d_out;

  int*    gidx = (int*)d_ws;
  float*  gw   = (float*)((char*)d_ws + (size_t)NPATCH * 2 * sizeof(int));
  bf16x8* wpk  = (bf16x8*)((char*)d_ws + (size_t)NPATCH * 4 * sizeof(int));  // 64KB offset, 256KB
  const size_t ws_need = (size_t)NPATCH * 4 * sizeof(int) + 256 * 1024;
  const bool packed = ws_size >= ws_need;   // ws_size constant across calls -> capture-safe

  gate_kernel<<<NPATCH / 8, 256, 0, stream>>>(x, gate_w1, gate_b1, gate_w2, gate_b2, gidx, gw);
  if (packed) {
    prep_kernel<<<64, 256, 0, stream>>>(pw2_w, wpk);
    expert_kernel<true><<<NPATCH, 256, 0, stream>>>(x, dw1_w, dw1_b, pw1_w, pw1_b,
                                                    dw2_w, dw2_b, wpk, pw2_w, pw2_b,
                                                    gidx, gw, out);
  } else {
    expert_kernel<false><<<NPATCH, 256, 0, stream>>>(x, dw1_w, dw1_b, pw1_w, pw1_b,
                                                     dw2_w, dw2_b, wpk, pw2_w, pw2_b,
                                                     gidx, gw, out);
  }
}

// Round 8
// 372.643 us; speedup vs baseline: 1.8016x; 1.2569x over previous
//
#include <hip/hip_runtime.h>

#define NPATCH 4096

typedef __attribute__((ext_vector_type(8))) __bf16 bf16x8;
typedef __attribute__((ext_vector_type(4))) __bf16 bf16x4;
typedef __attribute__((ext_vector_type(4))) float f32x4;

// ---------------- prep kernel: pack pw2 weights bf16 in MFMA fragment order ----------------
// wpk[(((e*4+kt)*8+nt)*64 + l)] = 8 bf16 = pw2_w[e][nt*16+(l&15)][kt*32+(l>>4)*8 .. +8]
__global__ __launch_bounds__(256) void prep_kernel(const float* __restrict__ pw2_w,
                                                   bf16x8* __restrict__ wpk) {
  int tid = blockIdx.x * 256 + threadIdx.x;    // 64 blocks -> 16384 threads
  int l = tid & 63, nt = (tid >> 6) & 7, kt = (tid >> 9) & 3, e = tid >> 11;
  int n = nt * 16 + (l & 15);
  int k = kt * 32 + (l >> 4) * 8;
  const float* src = &pw2_w[((size_t)(e * 128 + n)) * 128 + k];
  float4 a = *(const float4*)src;
  float4 b = *(const float4*)(src + 4);
  bf16x8 r = { (__bf16)a.x, (__bf16)a.y, (__bf16)a.z, (__bf16)a.w,
               (__bf16)b.x, (__bf16)b.y, (__bf16)b.z, (__bf16)b.w };
  wpk[tid] = r;    // tid == ((e*4+kt)*8+nt)*64 + l
}

// ---------------- gate kernel ----------------
// 512 blocks x 512 threads; block = 8 patches x 128 d; thread = 2 patches x 1 d.
// Patches staged in LDS one channel at a time (3 stages, 3 barriers total);
// w1 streamed from L2 per-lane coalesced (w1[k*128+d], 64 consecutive dwords
// per wave). NO barriers inside the 1024-k channel loop. Per-output FMA
// association identical to all passing rounds (sequential j in 32-chunk,
// chunks summed in order).
__global__ __launch_bounds__(512, 4) void gate_kernel(
    const float* __restrict__ x, const float* __restrict__ w1,
    const float* __restrict__ b1, const float* __restrict__ w2,
    const float* __restrict__ b2, int* __restrict__ gidx,
    float* __restrict__ gw)
{
  __shared__ float As[8][1024];   // 32 KB: 8 patches x one channel
  __shared__ float hs[8][128];
  __shared__ float ls[8][8];

  const int t   = threadIdx.x;
  const int p0  = blockIdx.x * 8;
  const int d   = t & 127;
  const int grp = t >> 7;          // 0..3
  const int pa  = grp * 2, pb = grp * 2 + 1;

  float acc0 = 0.f, acc1 = 0.f;

  for (int c = 0; c < 3; ++c) {
    // ---- stage channel c of all 8 patches (2048 float4, 4 per thread) ----
#pragma unroll
    for (int it = 0; it < 4; ++it) {
      int i = t + it * 512;
      int p = i >> 8, rem = i & 255, r = rem >> 3, j4 = (rem & 7) * 4;
      int gp = p0 + p;
      int bb = gp >> 8, ph = (gp >> 4) & 15, pwc = gp & 15;
      *(float4*)&As[p][r * 32 + j4] =
          *(const float4*)&x[((size_t)(bb * 3 + c) * 512 + ph * 32 + r) * 512 + pwc * 32 + j4];
    }
    __syncthreads();

    const float* wdp = w1 + (size_t)c * 131072 + d;   // c*1024*128
    for (int ch = 0; ch < 32; ++ch) {
      // preload 32 B-values (coalesced across the wave, L2-resident)
      float bv[32];
#pragma unroll
      for (int j = 0; j < 32; ++j) bv[j] = wdp[(ch * 32 + j) * 128];

      const int kl = ch * 32;
      float ca = 0.f, cb = 0.f;
#pragma unroll
      for (int q = 0; q < 8; ++q) {
        float4 a0 = *(const float4*)&As[pa][kl + q * 4];
        float4 a1 = *(const float4*)&As[pb][kl + q * 4];
        ca = fmaf(a0.x, bv[q * 4 + 0], ca);
        ca = fmaf(a0.y, bv[q * 4 + 1], ca);
        ca = fmaf(a0.z, bv[q * 4 + 2], ca);
        ca = fmaf(a0.w, bv[q * 4 + 3], ca);
        cb = fmaf(a1.x, bv[q * 4 + 0], cb);
        cb = fmaf(a1.y, bv[q * 4 + 1], cb);
        cb = fmaf(a1.z, bv[q * 4 + 2], cb);
        cb = fmaf(a1.w, bv[q * 4 + 3], cb);
      }
      acc0 += ca;     // per-32-chunk accumulate: matches all passing rounds
      acc1 += cb;
    }
    __syncthreads();   // protect As before next channel's restage
  }

  hs[pa][d] = fmaxf(acc0 + b1[d], 0.f);
  hs[pb][d] = fmaxf(acc1 + b1[d], 0.f);
  __syncthreads();

  if (t < 64) {                       // (patch, expert) pairs
    int p = t >> 3, e = t & 7;
    float s = 0.f;
    for (int d0 = 0; d0 < 128; d0 += 32) {
      float cs = 0.f;
#pragma unroll
      for (int dd = 0; dd < 32; ++dd)
        cs = fmaf(hs[p][d0 + dd], w2[(d0 + dd) * 8 + e], cs);
      s += cs;
    }
    ls[p][e] = s + b2[e];
  }
  __syncthreads();

  if (t < 8) {
    int gp = p0 + t;
    float v[8];
#pragma unroll
    for (int e = 0; e < 8; ++e) v[e] = ls[t][e];
    int e0 = 0;
#pragma unroll
    for (int e = 1; e < 8; ++e) if (v[e] > v[e0]) e0 = e;
    int e1 = (e0 == 0) ? 1 : 0;
#pragma unroll
    for (int e = 0; e < 8; ++e) { if (e != e0 && v[e] > v[e1]) e1 = e; }
    float bexp = expf(v[e1] - v[e0]);
    float inv  = 1.f / (1.f + bexp);
    gidx[gp * 2 + 0] = e0;
    gidx[gp * 2 + 1] = e1;
    gw[gp * 2 + 0] = inv;
    gw[gp * 2 + 1] = bexp * inv;
  }
}

// ---------------- expert kernels ----------------
// 4096 blocks (one per patch), 256 threads. pw2 on bf16 MFMA.
// Packed variant: B-fragments from prepacked global (L2-resident), 37 KB LDS
// -> 4 blocks/CU. Fallback variant (own kernel so its LDS doesn't tax the
// packed path): weights staged to LDS per expert, 71 KB.

#define EXPERT_COMMON_PRE                                                          \
  __shared__ float  ps[3][32][36];                                                 \
  __shared__ float  y1s[3][256];                                                   \
  __shared__ __bf16 y3b[64][136];                                                  \
  __shared__ float  posum[4][128];                                                 \
  __shared__ float  outbuf[128];                                                   \
  const int t  = threadIdx.x;                                                      \
  const int gp = blockIdx.x;                                                       \
  const int b = gp >> 8, ph = (gp >> 4) & 15, pw = gp & 15;                        \
  const int l = t & 63, wv = t >> 6;                                               \
  _Pragma("unroll")                                                                \
  for (int it = 0; it < 3; ++it) {                                                 \
    int f4i = t + 256 * it;                                                        \
    int c = f4i >> 8, r = (f4i >> 3) & 31, j4 = f4i & 7;                           \
    *(float4*)&ps[c][r][j4 * 4] =                                                  \
        *(const float4*)&x[((size_t)(b * 3 + c) * 512 + ph * 32 + r) * 512 +       \
                           pw * 32 + j4 * 4];                                      \
  }                                                                                \
  if (t < 128) outbuf[t] = 0.f;                                                    \
  const int dd   = t >> 1;                                                         \
  const int half = t & 1;                                                          \
  __syncthreads();

#define EXPERT_PHASES_1_2                                                          \
    for (int oi = t; oi < 768; oi += 256) {                                        \
      int c = oi >> 8, p = (oi >> 4) & 15, q = oi & 15;                            \
      float a = dw1_b[e * 3 + c];                                                  \
      const float* wp_ = &dw1_w[(e * 3 + c) * 9];                                  \
      _Pragma("unroll")                                                            \
      for (int di = 0; di < 3; ++di) {                                             \
        int ii = 2 * p + di - 1;                                                   \
        if (ii < 0) continue;                                                      \
        _Pragma("unroll")                                                          \
        for (int dj = 0; dj < 3; ++dj) {                                           \
          int jj = 2 * q + dj - 1;                                                 \
          if (jj < 0) continue;                                                    \
          a = fmaf(wp_[di * 3 + dj], ps[c][ii][jj], a);                            \
        }                                                                          \
      }                                                                            \
      y1s[c][p * 16 + q] = fmaxf(a, 0.f);                                          \
    }                                                                              \
    __syncthreads();                                                               \
    {                                                                              \
      const float pwa = pw1_w[(e * 128 + dd) * 3 + 0];                             \
      const float pwb = pw1_w[(e * 128 + dd) * 3 + 1];                             \
      const float pwc = pw1_w[(e * 128 + dd) * 3 + 2];                             \
      const float pb  = pw1_b[e * 128 + dd];                                       \
      float dwv[9];                                                                \
      _Pragma("unroll")                                                            \
      for (int i = 0; i < 9; ++i) dwv[i] = dw2_w[(e * 128 + dd) * 9 + i];          \
      const float db = dw2_b[e * 128 + dd];                                        \
      for (int u = half * 4; u < half * 4 + 4; ++u) {                              \
        float vacc[8];                                                             \
        _Pragma("unroll")                                                          \
        for (int v = 0; v < 8; ++v) vacc[v] = db;                                  \
        _Pragma("unroll")                                                          \
        for (int di = 0; di < 3; ++di) {                                           \
          int ii = 2 * u + di - 1;                                                 \
          if (ii < 0) continue;                                                    \
          float y2row[16];                                                         \
          _Pragma("unroll")                                                        \
          for (int q4 = 0; q4 < 4; ++q4) {                                         \
            float4 a  = *(const float4*)&y1s[0][ii * 16 + q4 * 4];                 \
            float4 bq = *(const float4*)&y1s[1][ii * 16 + q4 * 4];                 \
            float4 cq = *(const float4*)&y1s[2][ii * 16 + q4 * 4];                 \
            y2row[q4 * 4 + 0] = fmaxf(fmaf(pwa, a.x, fmaf(pwb, bq.x, fmaf(pwc, cq.x, pb))), 0.f); \
            y2row[q4 * 4 + 1] = fmaxf(fmaf(pwa, a.y, fmaf(pwb, bq.y, fmaf(pwc, cq.y, pb))), 0.f); \
            y2row[q4 * 4 + 2] = fmaxf(fmaf(pwa, a.z, fmaf(pwb, bq.z, fmaf(pwc, cq.z, pb))), 0.f); \
            y2row[q4 * 4 + 3] = fmaxf(fmaf(pwa, a.w, fmaf(pwb, bq.w, fmaf(pwc, cq.w, pb))), 0.f); \
          }                                                                        \
          _Pragma("unroll")                                                        \
          for (int v = 0; v < 8; ++v) {                                            \
            _Pragma("unroll")                                                      \
            for (int dj = 0; dj < 3; ++dj) {                                       \
              int jj = 2 * v + dj - 1;                                             \
              if (jj < 0) continue;                                                \
              vacc[v] = fmaf(dwv[di * 3 + dj], y2row[jj], vacc[v]);                \
            }                                                                      \
          }                                                                        \
        }                                                                          \
        _Pragma("unroll")                                                          \
        for (int v = 0; v < 8; ++v)                                                \
          y3b[u * 8 + v][dd] = (__bf16)fmaxf(vacc[v], 0.f);                        \
      }                                                                            \
    }

#define EXPERT_EPILOG                                                              \
    _Pragma("unroll")                                                              \
    for (int nt = 0; nt < 8; ++nt) {                                               \
      float bias = pw2_b[e * 128 + nt * 16 + (l & 15)];                            \
      float s = fmaxf(acc[nt][0] + bias, 0.f) + fmaxf(acc[nt][1] + bias, 0.f)      \
              + fmaxf(acc[nt][2] + bias, 0.f) + fmaxf(acc[nt][3] + bias, 0.f);     \
      s += __shfl_xor(s, 16);                                                      \
      s += __shfl_xor(s, 32);                                                      \
      if (l < 16) posum[wv][nt * 16 + l] = s;                                      \
    }

__global__ __launch_bounds__(256, 4) void expert_packed(
    const float* __restrict__ x,
    const float* __restrict__ dw1_w, const float* __restrict__ dw1_b,
    const float* __restrict__ pw1_w, const float* __restrict__ pw1_b,
    const float* __restrict__ dw2_w, const float* __restrict__ dw2_b,
    const bf16x8* __restrict__ wpk, const float* __restrict__ pw2_b,
    const int* __restrict__ gidx, const float* __restrict__ gw,
    float* __restrict__ out)
{
  EXPERT_COMMON_PRE
  for (int k = 0; k < 2; ++k) {
    const int   e  = gidx[gp * 2 + k];
    const float wk = gw[gp * 2 + k];
    EXPERT_PHASES_1_2
    __syncthreads();
    {
      f32x4 acc[8];
#pragma unroll
      for (int nt = 0; nt < 8; ++nt) acc[nt] = (f32x4){0.f, 0.f, 0.f, 0.f};
      const int row  = wv * 16 + (l & 15);
      const int kofs = (l >> 4) * 8;
      bf16x8 afrag[4];
#pragma unroll
      for (int kt = 0; kt < 4; ++kt)
        afrag[kt] = *(const bf16x8*)&y3b[row][kt * 32 + kofs];
      const bf16x8* wb = wpk + (size_t)e * 2048 + l;
#pragma unroll
      for (int kt = 0; kt < 4; ++kt) {
        bf16x8 bf[8];
#pragma unroll
        for (int nt = 0; nt < 8; ++nt) bf[nt] = wb[(kt * 8 + nt) * 64];
#pragma unroll
        for (int nt = 0; nt < 8; ++nt)
          acc[nt] = __builtin_amdgcn_mfma_f32_16x16x32_bf16(afrag[kt], bf[nt], acc[nt], 0, 0, 0);
      }
      EXPERT_EPILOG
    }
    __syncthreads();
    if (t < 128)
      outbuf[t] += wk * 0.015625f *
                   (posum[0][t] + posum[1][t] + posum[2][t] + posum[3][t]);
    __syncthreads();
  }
  if (t < 128)
    out[((size_t)(b * 128 + t) * 16 + ph) * 16 + pw] = outbuf[t];
}

__global__ __launch_bounds__(256) void expert_fb(
    const float* __restrict__ x,
    const float* __restrict__ dw1_w, const float* __restrict__ dw1_b,
    const float* __restrict__ pw1_w, const float* __restrict__ pw1_b,
    const float* __restrict__ dw2_w, const float* __restrict__ dw2_b,
    const float* __restrict__ pw2_w, const float* __restrict__ pw2_b,
    const int* __restrict__ gidx, const float* __restrict__ gw,
    float* __restrict__ out)
{
  __shared__ __bf16 wlds[128][136];
  EXPERT_COMMON_PRE
  for (int k = 0; k < 2; ++k) {
    const int   e  = gidx[gp * 2 + k];
    const float wk = gw[gp * 2 + k];
    EXPERT_PHASES_1_2
    for (int i4 = t; i4 < 4096; i4 += 256) {
      int n = i4 >> 5, kq = i4 & 31;
      float4 w4 = *(const float4*)&pw2_w[((size_t)(e * 128 + n)) * 128 + kq * 4];
      bf16x4 pk = { (__bf16)w4.x, (__bf16)w4.y, (__bf16)w4.z, (__bf16)w4.w };
      *(bf16x4*)&wlds[n][kq * 4] = pk;
    }
    __syncthreads();
    {
      f32x4 acc[8];
#pragma unroll
      for (int nt = 0; nt < 8; ++nt) acc[nt] = (f32x4){0.f, 0.f, 0.f, 0.f};
      const int row  = wv * 16 + (l & 15);
      const int kofs = (l >> 4) * 8;
      bf16x8 afrag[4];
#pragma unroll
      for (int kt = 0; kt < 4; ++kt)
        afrag[kt] = *(const bf16x8*)&y3b[row][kt * 32 + kofs];
#pragma unroll
      for (int kt = 0; kt < 4; ++kt) {
#pragma unroll
        for (int nt = 0; nt < 8; ++nt) {
          bf16x8 bfrag = *(const bf16x8*)&wlds[nt * 16 + (l & 15)][kt * 32 + kofs];
          acc[nt] = __builtin_amdgcn_mfma_f32_16x16x32_bf16(afrag[kt], bfrag, acc[nt], 0, 0, 0);
        }
      }
      EXPERT_EPILOG
    }
    __syncthreads();
    if (t < 128)
      outbuf[t] += wk * 0.015625f *
                   (posum[0][t] + posum[1][t] + posum[2][t] + posum[3][t]);
    __syncthreads();
  }
  if (t < 128)
    out[((size_t)(b * 128 + t) * 16 + ph) * 16 + pw] = outbuf[t];
}

extern "C" void kernel_launch(void* const* d_in, const int* in_sizes, int n_in,
                              void* d_out, int out_size, void* d_ws, size_t ws_size,
                              hipStream_t stream) {
  const float* x       = (const float*)d_in[0];
  const float* gate_w1 = (const float*)d_in[1];
  const float* gate_b1 = (const float*)d_in[2];
  const float* gate_w2 = (const float*)d_in[3];
  const float* gate_b2 = (const float*)d_in[4];
  const float* dw1_w   = (const float*)d_in[5];
  const float* dw1_b   = (const float*)d_in[6];
  const float* pw1_w   = (const float*)d_in[7];
  const float* pw1_b   = (const float*)d_in[8];
  const float* dw2_w   = (const float*)d_in[9];
  const float* dw2_b   = (const float*)d_in[10];
  const float* pw2_w   = (const float*)d_in[11];
  const float* pw2_b   = (const float*)d_in[12];
  float* out = (float*)d_out;

  int*    gidx = (int*)d_ws;
  float*  gw   = (float*)((char*)d_ws + (size_t)NPATCH * 2 * sizeof(int));
  bf16x8* wpk  = (bf16x8*)((char*)d_ws + (size_t)NPATCH * 4 * sizeof(int));  // 64KB offset, 256KB
  const size_t ws_need = (size_t)NPATCH * 4 * sizeof(int) + 256 * 1024;
  const bool packed = ws_size >= ws_need;   // ws_size constant across calls -> capture-safe

  gate_kernel<<<NPATCH / 8, 512, 0, stream>>>(x, gate_w1, gate_b1, gate_w2, gate_b2, gidx, gw);
  if (packed) {
    prep_kernel<<<64, 256, 0, stream>>>(pw2_w, wpk);
    expert_packed<<<NPATCH, 256, 0, stream>>>(x, dw1_w, dw1_b, pw1_w, pw1_b,
                                              dw2_w, dw2_b, wpk, pw2_b, gidx, gw, out);
  } else {
    expert_fb<<<NPATCH, 256, 0, stream>>>(x, dw1_w, dw1_b, pw1_w, pw1_b,
                                          dw2_w, dw2_b, pw2_w, pw2_b, gidx, gw, out);
  }
}

// Round 9
// 322.727 us; speedup vs baseline: 2.0803x; 1.1547x over previous
//
#include <hip/hip_runtime.h>

#define NPATCH 4096
#define NFRAG 49152   // 96 ktiles * 8 ntiles * 64 lanes

typedef __attribute__((ext_vector_type(8))) __bf16 bf16x8;
typedef __attribute__((ext_vector_type(4))) __bf16 bf16x4;
typedef __attribute__((ext_vector_type(4))) float f32x4;

// ---------------- prep: pack pw2 weights bf16 in MFMA fragment order ----------------
__global__ __launch_bounds__(256) void prep_kernel(const float* __restrict__ pw2_w,
                                                   bf16x8* __restrict__ wpk) {
  int tid = blockIdx.x * 256 + threadIdx.x;    // 64 blocks -> 16384 threads
  int l = tid & 63, nt = (tid >> 6) & 7, kt = (tid >> 9) & 3, e = tid >> 11;
  int n = nt * 16 + (l & 15);
  int k = kt * 32 + (l >> 4) * 8;
  const float* src = &pw2_w[((size_t)(e * 128 + n)) * 128 + k];
  float4 a = *(const float4*)src;
  float4 b = *(const float4*)(src + 4);
  bf16x8 r = { (__bf16)a.x, (__bf16)a.y, (__bf16)a.z, (__bf16)a.w,
               (__bf16)b.x, (__bf16)b.y, (__bf16)b.z, (__bf16)b.w };
  wpk[tid] = r;
}

// ---------------- prep: split gate w1 into hi/lo bf16 MFMA B-fragments ----------------
// B[n][k]: lane l holds n = nt*16+(l&15), k = ktg*32+(l>>4)*8 .. +8
// w1f[(ktg*8+nt)*64+l] = hi frag;  w1f[NFRAG + same] = lo frag
__global__ __launch_bounds__(256) void prep_w1(const float* __restrict__ w1,
                                               bf16x8* __restrict__ w1f) {
  int tid = blockIdx.x * 256 + threadIdx.x;    // 192 blocks -> 49152 threads
  int l = tid & 63, nt = (tid >> 6) & 7, ktg = tid >> 9;
  int k0 = ktg * 32 + (l >> 4) * 8, d = nt * 16 + (l & 15);
  bf16x8 h, lo;
#pragma unroll
  for (int j = 0; j < 8; ++j) {
    float v = w1[(size_t)(k0 + j) * 128 + d];
    __bf16 hv = (__bf16)v;
    h[j] = hv;
    lo[j] = (__bf16)(v - (float)hv);
  }
  w1f[tid] = h;
  w1f[NFRAG + tid] = lo;
}

// ---------------- gate via MFMA (2-term bf16 split) ----------------
// 256 blocks x 512 threads; block = 16 patches x 128 d; wave wv owns n-tile wv.
// K: 12 chunks of 256 (double-buffered LDS, issue-early/write-late staging).
// acc = Ah*Bh + Ah*Bl + Al*Bh, rotated over 4 regs; summed in fixed order.
__global__ __launch_bounds__(512) void gate_mfma(
    const float* __restrict__ x, const bf16x8* __restrict__ w1f,
    const float* __restrict__ b1, const float* __restrict__ w2,
    const float* __restrict__ b2, int* __restrict__ gidx,
    float* __restrict__ gw)
{
  __shared__ float As[2][16][260];   // pad 260: balanced bank groups for b128 reads
  __shared__ float hs[16][128];
  __shared__ float ls[16][8];

  const int t  = threadIdx.x;
  const int p0 = blockIdx.x * 16;
  const int l  = t & 63;
  const int wv = t >> 6;          // n-tile 0..7
  const int mrow  = l & 15;
  const int kslot = l >> 4;

  f32x4 accA[4], accB[4];
#pragma unroll
  for (int i = 0; i < 4; ++i) {
    accA[i] = (f32x4){0.f, 0.f, 0.f, 0.f};
    accB[i] = (f32x4){0.f, 0.f, 0.f, 0.f};
  }

  // staging addresses: i = t + it*512 -> p=i>>6, rr=(i>>3)&7, j4=i&7
  int sp[2], srr[2], sj4[2];
  size_t sbase[2];
#pragma unroll
  for (int it = 0; it < 2; ++it) {
    int i = t + it * 512;
    sp[it] = i >> 6; srr[it] = (i >> 3) & 7; sj4[it] = i & 7;
    int gp = p0 + sp[it];
    int bb = gp >> 8, ph = (gp >> 4) & 15, pwc = gp & 15;
    sbase[it] = ((size_t)(bb * 3) * 512 + ph * 32 + srr[it]) * 512 + pwc * 32 + sj4[it] * 4;
  }
  // chunk ch: c = ch>>2, r0 = (ch&3)*8 ; x offset = c*262144 + r0*512
#define GX(it, ch) (sbase[it] + (size_t)((ch) >> 2) * 262144 + (size_t)(((ch) & 3) * 8) * 512)

  // prologue: stage chunk 0 -> buf 0
#pragma unroll
  for (int it = 0; it < 2; ++it)
    *(float4*)&As[0][sp[it]][srr[it] * 32 + sj4[it] * 4] = *(const float4*)&x[GX(it, 0)];
  __syncthreads();

  for (int ch = 0; ch < 12; ++ch) {
    const int buf = ch & 1;
    float4 r0, r1;
    if (ch + 1 < 12) {                 // issue next chunk's loads early
      r0 = *(const float4*)&x[GX(0, ch + 1)];
      r1 = *(const float4*)&x[GX(1, ch + 1)];
    }
#pragma unroll
    for (int ktl = 0; ktl < 8; ++ktl) {
      const int ktg = ch * 8 + ktl;
      float4 a0 = *(const float4*)&As[buf][mrow][ktl * 32 + kslot * 8];
      float4 a1 = *(const float4*)&As[buf][mrow][ktl * 32 + kslot * 8 + 4];
      float av[8] = {a0.x, a0.y, a0.z, a0.w, a1.x, a1.y, a1.z, a1.w};
      bf16x8 ah, al;
#pragma unroll
      for (int j = 0; j < 8; ++j) {
        __bf16 hv = (__bf16)av[j];
        ah[j] = hv;
        al[j] = (__bf16)(av[j] - (float)hv);
      }
      bf16x8 bh = w1f[(ktg * 8 + wv) * 64 + l];
      bf16x8 bl = w1f[NFRAG + (ktg * 8 + wv) * 64 + l];
      const int r = ktl & 3;
      accA[r] = __builtin_amdgcn_mfma_f32_16x16x32_bf16(ah, bh, accA[r], 0, 0, 0);
      accB[r] = __builtin_amdgcn_mfma_f32_16x16x32_bf16(ah, bl, accB[r], 0, 0, 0);
      accB[r] = __builtin_amdgcn_mfma_f32_16x16x32_bf16(al, bh, accB[r], 0, 0, 0);
    }
    if (ch + 1 < 12) {                 // write-late into the other buffer
      *(float4*)&As[buf ^ 1][sp[0]][srr[0] * 32 + sj4[0] * 4] = r0;
      *(float4*)&As[buf ^ 1][sp[1]][srr[1] * 32 + sj4[1] * 4] = r1;
    }
    __syncthreads();
  }
#undef GX

  // epilogue: fixed-order reduction, bias, relu -> hs
  {
    f32x4 sA = (accA[0] + accA[1]) + (accA[2] + accA[3]);
    f32x4 sB = (accB[0] + accB[1]) + (accB[2] + accB[3]);
    const int d = wv * 16 + mrow;
    const float bb1 = b1[d];
#pragma unroll
    for (int r = 0; r < 4; ++r) {
      int m = kslot * 4 + r;
      hs[m][d] = fmaxf(sA[r] + sB[r] + bb1, 0.f);
    }
  }
  __syncthreads();

  if (t < 128) {                       // (patch, expert) logits — same numerics as r1/r4
    int p = t >> 3, e = t & 7;
    float s = 0.f;
    for (int d0 = 0; d0 < 128; d0 += 32) {
      float cs = 0.f;
#pragma unroll
      for (int dd = 0; dd < 32; ++dd)
        cs = fmaf(hs[p][d0 + dd], w2[(d0 + dd) * 8 + e], cs);
      s += cs;
    }
    ls[p][e] = s + b2[e];
  }
  __syncthreads();

  if (t < 16) {
    int gp = p0 + t;
    float v[8];
#pragma unroll
    for (int e = 0; e < 8; ++e) v[e] = ls[t][e];
    int e0 = 0;
#pragma unroll
    for (int e = 1; e < 8; ++e) if (v[e] > v[e0]) e0 = e;
    int e1 = (e0 == 0) ? 1 : 0;
#pragma unroll
    for (int e = 0; e < 8; ++e) { if (e != e0 && v[e] > v[e1]) e1 = e; }
    float bexp = expf(v[e1] - v[e0]);
    float inv  = 1.f / (1.f + bexp);
    gidx[gp * 2 + 0] = e0;
    gidx[gp * 2 + 1] = e1;
    gw[gp * 2 + 0] = inv;
    gw[gp * 2 + 1] = bexp * inv;
  }
}

// ---------------- fallback gate (r8, proven) ----------------
__global__ __launch_bounds__(512, 4) void gate_kernel(
    const float* __restrict__ x, const float* __restrict__ w1,
    const float* __restrict__ b1, const float* __restrict__ w2,
    const float* __restrict__ b2, int* __restrict__ gidx,
    float* __restrict__ gw)
{
  __shared__ float As[8][1024];
  __shared__ float hs[8][128];
  __shared__ float ls[8][8];

  const int t   = threadIdx.x;
  const int p0  = blockIdx.x * 8;
  const int d   = t & 127;
  const int grp = t >> 7;
  const int pa  = grp * 2, pb = grp * 2 + 1;

  float acc0 = 0.f, acc1 = 0.f;

  for (int c = 0; c < 3; ++c) {
#pragma unroll
    for (int it = 0; it < 4; ++it) {
      int i = t + it * 512;
      int p = i >> 8, rem = i & 255, r = rem >> 3, j4 = (rem & 7) * 4;
      int gp = p0 + p;
      int bb = gp >> 8, ph = (gp >> 4) & 15, pwc = gp & 15;
      *(float4*)&As[p][r * 32 + j4] =
          *(const float4*)&x[((size_t)(bb * 3 + c) * 512 + ph * 32 + r) * 512 + pwc * 32 + j4];
    }
    __syncthreads();

    const float* wdp = w1 + (size_t)c * 131072 + d;
    for (int ch = 0; ch < 32; ++ch) {
      float bv[32];
#pragma unroll
      for (int j = 0; j < 32; ++j) bv[j] = wdp[(ch * 32 + j) * 128];
      const int kl = ch * 32;
      float ca = 0.f, cb = 0.f;
#pragma unroll
      for (int q = 0; q < 8; ++q) {
        float4 a0 = *(const float4*)&As[pa][kl + q * 4];
        float4 a1 = *(const float4*)&As[pb][kl + q * 4];
        ca = fmaf(a0.x, bv[q * 4 + 0], ca); ca = fmaf(a0.y, bv[q * 4 + 1], ca);
        ca = fmaf(a0.z, bv[q * 4 + 2], ca); ca = fmaf(a0.w, bv[q * 4 + 3], ca);
        cb = fmaf(a1.x, bv[q * 4 + 0], cb); cb = fmaf(a1.y, bv[q * 4 + 1], cb);
        cb = fmaf(a1.z, bv[q * 4 + 2], cb); cb = fmaf(a1.w, bv[q * 4 + 3], cb);
      }
      acc0 += ca; acc1 += cb;
    }
    __syncthreads();
  }

  hs[pa][d] = fmaxf(acc0 + b1[d], 0.f);
  hs[pb][d] = fmaxf(acc1 + b1[d], 0.f);
  __syncthreads();

  if (t < 64) {
    int p = t >> 3, e = t & 7;
    float s = 0.f;
    for (int d0 = 0; d0 < 128; d0 += 32) {
      float cs = 0.f;
#pragma unroll
      for (int dd = 0; dd < 32; ++dd)
        cs = fmaf(hs[p][d0 + dd], w2[(d0 + dd) * 8 + e], cs);
      s += cs;
    }
    ls[p][e] = s + b2[e];
  }
  __syncthreads();

  if (t < 8) {
    int gp = p0 + t;
    float v[8];
#pragma unroll
    for (int e = 0; e < 8; ++e) v[e] = ls[t][e];
    int e0 = 0;
#pragma unroll
    for (int e = 1; e < 8; ++e) if (v[e] > v[e0]) e0 = e;
    int e1 = (e0 == 0) ? 1 : 0;
#pragma unroll
    for (int e = 0; e < 8; ++e) { if (e != e0 && v[e] > v[e1]) e1 = e; }
    float bexp = expf(v[e1] - v[e0]);
    float inv  = 1.f / (1.f + bexp);
    gidx[gp * 2 + 0] = e0;
    gidx[gp * 2 + 1] = e1;
    gw[gp * 2 + 0] = inv;
    gw[gp * 2 + 1] = bexp * inv;
  }
}

// ---------------- expert kernels (unchanged from r8) ----------------
#define EXPERT_COMMON_PRE                                                          \
  __shared__ float  ps[3][32][36];                                                 \
  __shared__ float  y1s[3][256];                                                   \
  __shared__ __bf16 y3b[64][136];                                                  \
  __shared__ float  posum[4][128];                                                 \
  __shared__ float  outbuf[128];                                                   \
  const int t  = threadIdx.x;                                                      \
  const int gp = blockIdx.x;                                                       \
  const int b = gp >> 8, ph = (gp >> 4) & 15, pw = gp & 15;                        \
  const int l = t & 63, wv = t >> 6;                                               \
  _Pragma("unroll")                                                                \
  for (int it = 0; it < 3; ++it) {                                                 \
    int f4i = t + 256 * it;                                                        \
    int c = f4i >> 8, r = (f4i >> 3) & 31, j4 = f4i & 7;                           \
    *(float4*)&ps[c][r][j4 * 4] =                                                  \
        *(const float4*)&x[((size_t)(b * 3 + c) * 512 + ph * 32 + r) * 512 +       \
                           pw * 32 + j4 * 4];                                      \
  }                                                                                \
  if (t < 128) outbuf[t] = 0.f;                                                    \
  const int dd   = t >> 1;                                                         \
  const int half = t & 1;                                                          \
  __syncthreads();

#define EXPERT_PHASES_1_2                                                          \
    for (int oi = t; oi < 768; oi += 256) {                                        \
      int c = oi >> 8, p = (oi >> 4) & 15, q = oi & 15;                            \
      float a = dw1_b[e * 3 + c];                                                  \
      const float* wp_ = &dw1_w[(e * 3 + c) * 9];                                  \
      _Pragma("unroll")                                                            \
      for (int di = 0; di < 3; ++di) {                                             \
        int ii = 2 * p + di - 1;                                                   \
        if (ii < 0) continue;                                                      \
        _Pragma("unroll")                                                          \
        for (int dj = 0; dj < 3; ++dj) {                                           \
          int jj = 2 * q + dj - 1;                                                 \
          if (jj < 0) continue;                                                    \
          a = fmaf(wp_[di * 3 + dj], ps[c][ii][jj], a);                            \
        }                                                                          \
      }                                                                            \
      y1s[c][p * 16 + q] = fmaxf(a, 0.f);                                          \
    }                                                                              \
    __syncthreads();                                                               \
    {                                                                              \
      const float pwa = pw1_w[(e * 128 + dd) * 3 + 0];                             \
      const float pwb = pw1_w[(e * 128 + dd) * 3 + 1];                             \
      const float pwc = pw1_w[(e * 128 + dd) * 3 + 2];                             \
      const float pb  = pw1_b[e * 128 + dd];                                       \
      float dwv[9];                                                                \
      _Pragma("unroll")                                                            \
      for (int i = 0; i < 9; ++i) dwv[i] = dw2_w[(e * 128 + dd) * 9 + i];          \
      const float db = dw2_b[e * 128 + dd];                                        \
      for (int u = half * 4; u < half * 4 + 4; ++u) {                              \
        float vacc[8];                                                             \
        _Pragma("unroll")                                                          \
        for (int v = 0; v < 8; ++v) vacc[v] = db;                                  \
        _Pragma("unroll")                                                          \
        for (int di = 0; di < 3; ++di) {                                           \
          int ii = 2 * u + di - 1;                                                 \
          if (ii < 0) continue;                                                    \
          float y2row[16];                                                         \
          _Pragma("unroll")                                                        \
          for (int q4 = 0; q4 < 4; ++q4) {                                         \
            float4 a  = *(const float4*)&y1s[0][ii * 16 + q4 * 4];                 \
            float4 bq = *(const float4*)&y1s[1][ii * 16 + q4 * 4];                 \
            float4 cq = *(const float4*)&y1s[2][ii * 16 + q4 * 4];                 \
            y2row[q4 * 4 + 0] = fmaxf(fmaf(pwa, a.x, fmaf(pwb, bq.x, fmaf(pwc, cq.x, pb))), 0.f); \
            y2row[q4 * 4 + 1] = fmaxf(fmaf(pwa, a.y, fmaf(pwb, bq.y, fmaf(pwc, cq.y, pb))), 0.f); \
            y2row[q4 * 4 + 2] = fmaxf(fmaf(pwa, a.z, fmaf(pwb, bq.z, fmaf(pwc, cq.z, pb))), 0.f); \
            y2row[q4 * 4 + 3] = fmaxf(fmaf(pwa, a.w, fmaf(pwb, bq.w, fmaf(pwc, cq.w, pb))), 0.f); \
          }                                                                        \
          _Pragma("unroll")                                                        \
          for (int v = 0; v < 8; ++v) {                                            \
            _Pragma("unroll")                                                      \
            for (int dj = 0; dj < 3; ++dj) {                                       \
              int jj = 2 * v + dj - 1;                                             \
              if (jj < 0) continue;                                                \
              vacc[v] = fmaf(dwv[di * 3 + dj], y2row[jj], vacc[v]);                \
            }                                                                      \
          }                                                                        \
        }                                                                          \
        _Pragma("unroll")                                                          \
        for (int v = 0; v < 8; ++v)                                                \
          y3b[u * 8 + v][dd] = (__bf16)fmaxf(vacc[v], 0.f);                        \
      }                                                                            \
    }

#define EXPERT_EPILOG                                                              \
    _Pragma("unroll")                                                              \
    for (int nt = 0; nt < 8; ++nt) {                                               \
      float bias = pw2_b[e * 128 + nt * 16 + (l & 15)];                            \
      float s = fmaxf(acc[nt][0] + bias, 0.f) + fmaxf(acc[nt][1] + bias, 0.f)      \
              + fmaxf(acc[nt][2] + bias, 0.f) + fmaxf(acc[nt][3] + bias, 0.f);     \
      s += __shfl_xor(s, 16);                                                      \
      s += __shfl_xor(s, 32);                                                      \
      if (l < 16) posum[wv][nt * 16 + l] = s;                                      \
    }

__global__ __launch_bounds__(256, 4) void expert_packed(
    const float* __restrict__ x,
    const float* __restrict__ dw1_w, const float* __restrict__ dw1_b,
    const float* __restrict__ pw1_w, const float* __restrict__ pw1_b,
    const float* __restrict__ dw2_w, const float* __restrict__ dw2_b,
    const bf16x8* __restrict__ wpk, const float* __restrict__ pw2_b,
    const int* __restrict__ gidx, const float* __restrict__ gw,
    float* __restrict__ out)
{
  EXPERT_COMMON_PRE
  for (int k = 0; k < 2; ++k) {
    const int   e  = gidx[gp * 2 + k];
    const float wk = gw[gp * 2 + k];
    EXPERT_PHASES_1_2
    __syncthreads();
    {
      f32x4 acc[8];
#pragma unroll
      for (int nt = 0; nt < 8; ++nt) acc[nt] = (f32x4){0.f, 0.f, 0.f, 0.f};
      const int row  = wv * 16 + (l & 15);
      const int kofs = (l >> 4) * 8;
      bf16x8 afrag[4];
#pragma unroll
      for (int kt = 0; kt < 4; ++kt)
        afrag[kt] = *(const bf16x8*)&y3b[row][kt * 32 + kofs];
      const bf16x8* wb = wpk + (size_t)e * 2048 + l;
#pragma unroll
      for (int kt = 0; kt < 4; ++kt) {
        bf16x8 bf[8];
#pragma unroll
        for (int nt = 0; nt < 8; ++nt) bf[nt] = wb[(kt * 8 + nt) * 64];
#pragma unroll
        for (int nt = 0; nt < 8; ++nt)
          acc[nt] = __builtin_amdgcn_mfma_f32_16x16x32_bf16(afrag[kt], bf[nt], acc[nt], 0, 0, 0);
      }
      EXPERT_EPILOG
    }
    __syncthreads();
    if (t < 128)
      outbuf[t] += wk * 0.015625f *
                   (posum[0][t] + posum[1][t] + posum[2][t] + posum[3][t]);
    __syncthreads();
  }
  if (t < 128)
    out[((size_t)(b * 128 + t) * 16 + ph) * 16 + pw] = outbuf[t];
}

__global__ __launch_bounds__(256) void expert_fb(
    const float* __restrict__ x,
    const float* __restrict__ dw1_w, const float* __restrict__ dw1_b,
    const float* __restrict__ pw1_w, const float* __restrict__ pw1_b,
    const float* __restrict__ dw2_w, const float* __restrict__ dw2_b,
    const float* __restrict__ pw2_w, const float* __restrict__ pw2_b,
    const int* __restrict__ gidx, const float* __restrict__ gw,
    float* __restrict__ out)
{
  __shared__ __bf16 wlds[128][136];
  EXPERT_COMMON_PRE
  for (int k = 0; k < 2; ++k) {
    const int   e  = gidx[gp * 2 + k];
    const float wk = gw[gp * 2 + k];
    EXPERT_PHASES_1_2
    for (int i4 = t; i4 < 4096; i4 += 256) {
      int n = i4 >> 5, kq = i4 & 31;
      float4 w4 = *(const float4*)&pw2_w[((size_t)(e * 128 + n)) * 128 + kq * 4];
      bf16x4 pk = { (__bf16)w4.x, (__bf16)w4.y, (__bf16)w4.z, (__bf16)w4.w };
      *(bf16x4*)&wlds[n][kq * 4] = pk;
    }
    __syncthreads();
    {
      f32x4 acc[8];
#pragma unroll
      for (int nt = 0; nt < 8; ++nt) acc[nt] = (f32x4){0.f, 0.f, 0.f, 0.f};
      const int row  = wv * 16 + (l & 15);
      const int kofs = (l >> 4) * 8;
      bf16x8 afrag[4];
#pragma unroll
      for (int kt = 0; kt < 4; ++kt)
        afrag[kt] = *(const bf16x8*)&y3b[row][kt * 32 + kofs];
#pragma unroll
      for (int kt = 0; kt < 4; ++kt) {
#pragma unroll
        for (int nt = 0; nt < 8; ++nt) {
          bf16x8 bfrag = *(const bf16x8*)&wlds[nt * 16 + (l & 15)][kt * 32 + kofs];
          acc[nt] = __builtin_amdgcn_mfma_f32_16x16x32_bf16(afrag[kt], bfrag, acc[nt], 0, 0, 0);
        }
      }
      EXPERT_EPILOG
    }
    __syncthreads();
    if (t < 128)
      outbuf[t] += wk * 0.015625f *
                   (posum[0][t] + posum[1][t] + posum[2][t] + posum[3][t]);
    __syncthreads();
  }
  if (t < 128)
    out[((size_t)(b * 128 + t) * 16 + ph) * 16 + pw] = outbuf[t];
}

extern "C" void kernel_launch(void* const* d_in, const int* in_sizes, int n_in,
                              void* d_out, int out_size, void* d_ws, size_t ws_size,
                              hipStream_t stream) {
  const float* x       = (const float*)d_in[0];
  const float* gate_w1 = (const float*)d_in[1];
  const float* gate_b1 = (const float*)d_in[2];
  const float* gate_w2 = (const float*)d_in[3];
  const float* gate_b2 = (const float*)d_in[4];
  const float* dw1_w   = (const float*)d_in[5];
  const float* dw1_b   = (const float*)d_in[6];
  const float* pw1_w   = (const float*)d_in[7];
  const float* pw1_b   = (const float*)d_in[8];
  const float* dw2_w   = (const float*)d_in[9];
  const float* dw2_b   = (const float*)d_in[10];
  const float* pw2_w   = (const float*)d_in[11];
  const float* pw2_b   = (const float*)d_in[12];
  float* out = (float*)d_out;

  int*    gidx = (int*)d_ws;
  float*  gw   = (float*)((char*)d_ws + (size_t)NPATCH * 2 * sizeof(int));
  bf16x8* wpk  = (bf16x8*)((char*)d_ws + (size_t)NPATCH * 4 * sizeof(int));     // @64KB, 256KB
  bf16x8* w1f  = (bf16x8*)((char*)d_ws + (size_t)NPATCH * 4 * sizeof(int) + 256 * 1024);  // @320KB, 1.5MB
  const size_t ws_pack = (size_t)NPATCH * 4 * sizeof(int) + 256 * 1024;
  const size_t ws_full = ws_pack + (size_t)NFRAG * 2 * 16;
  const bool packed = ws_size >= ws_pack;
  const bool mfgate = ws_size >= ws_full;

  if (mfgate) {
    prep_w1<<<192, 256, 0, stream>>>(gate_w1, w1f);
    gate_mfma<<<NPATCH / 16, 512, 0, stream>>>(x, w1f, gate_b1, gate_w2, gate_b2, gidx, gw);
  } else {
    gate_kernel<<<NPATCH / 8, 512, 0, stream>>>(x, gate_w1, gate_b1, gate_w2, gate_b2, gidx, gw);
  }
  if (packed) {
    prep_kernel<<<64, 256, 0, stream>>>(pw2_w, wpk);
    expert_packed<<<NPATCH, 256, 0, stream>>>(x, dw1_w, dw1_b, pw1_w, pw1_b,
                                              dw2_w, dw2_b, wpk, pw2_b, gidx, gw, out);
  } else {
    expert_fb<<<NPATCH, 256, 0, stream>>>(x, dw1_w, dw1_b, pw1_w, pw1_b,
                                          dw2_w, dw2_b, pw2_w, pw2_b, gidx, gw, out);
  }
}

// Round 10
// 247.937 us; speedup vs baseline: 2.7078x; 1.3017x over previous
//
#include <hip/hip_runtime.h>

#define NPATCH 4096
#define NFRAG 49152   // 96 ktiles * 8 ntiles * 64 lanes

typedef __attribute__((ext_vector_type(8))) __bf16 bf16x8;
typedef __attribute__((ext_vector_type(4))) __bf16 bf16x4;
typedef __attribute__((ext_vector_type(4))) float f32x4;

// ---------------- prep: pack pw2 weights bf16 in MFMA fragment order ----------------
__global__ __launch_bounds__(256) void prep_kernel(const float* __restrict__ pw2_w,
                                                   bf16x8* __restrict__ wpk) {
  int tid = blockIdx.x * 256 + threadIdx.x;
  int l = tid & 63, nt = (tid >> 6) & 7, kt = (tid >> 9) & 3, e = tid >> 11;
  int n = nt * 16 + (l & 15);
  int k = kt * 32 + (l >> 4) * 8;
  const float* src = &pw2_w[((size_t)(e * 128 + n)) * 128 + k];
  float4 a = *(const float4*)src;
  float4 b = *(const float4*)(src + 4);
  bf16x8 r = { (__bf16)a.x, (__bf16)a.y, (__bf16)a.z, (__bf16)a.w,
               (__bf16)b.x, (__bf16)b.y, (__bf16)b.z, (__bf16)b.w };
  wpk[tid] = r;
}

// ---------------- prep: split gate w1 into hi/lo bf16 MFMA B-fragments ----------------
__global__ __launch_bounds__(256) void prep_w1(const float* __restrict__ w1,
                                               bf16x8* __restrict__ w1f) {
  int tid = blockIdx.x * 256 + threadIdx.x;    // 192 blocks -> 49152 threads
  int l = tid & 63, nt = (tid >> 6) & 7, ktg = tid >> 9;
  int k0 = ktg * 32 + (l >> 4) * 8, d = nt * 16 + (l & 15);
  bf16x8 h, lo;
#pragma unroll
  for (int j = 0; j < 8; ++j) {
    float v = w1[(size_t)(k0 + j) * 128 + d];
    __bf16 hv = (__bf16)v;
    h[j] = hv;
    lo[j] = (__bf16)(v - (float)hv);
  }
  w1f[tid] = h;
  w1f[NFRAG + tid] = lo;
}

// ---------------- gate via MFMA, software-pipelined ----------------
// 256 blocks x 512 threads; block = 16 patches x 128 d; wave wv owns n-tile wv.
// x pre-split to (Ah,Al) bf16 fragment-ordered LDS at stage time (split once per
// element; fragment reads are lane-contiguous 16B = conflict-free).
// B-fragments prefetched one full chunk ahead into registers (ping-pong).
// Arithmetic identical to the passing r9 gate (same split, same MFMA order).
__global__ __launch_bounds__(512) void gate_mfma(
    const float* __restrict__ x, const bf16x8* __restrict__ w1f,
    const float* __restrict__ b1, const float* __restrict__ w2,
    const float* __restrict__ b2, int* __restrict__ gidx,
    float* __restrict__ gw)
{
  __shared__ __bf16 Ah[2][8][64][8];   // 16 KB
  __shared__ __bf16 Al[2][8][64][8];   // 16 KB
  __shared__ float hs[16][128];
  __shared__ float ls[16][8];

  const int t  = threadIdx.x;
  const int p0 = blockIdx.x * 16;
  const int l  = t & 63;
  const int wv = t >> 6;          // 0..7, n-tile
  const int mrow  = l & 15;
  const int kslot = l >> 4;

  // staging coords: thread stages 2 float4; bijective over (p, j4, rr)
  const int sp   = l & 15;                    // patch within block
  const int sj4  = (l >> 4) + 4 * (wv & 1);   // 0..7 (float4 within 32-row)
  const int srr0 = (wv >> 1);                 // 0..3
  const int srr1 = 4 + (wv >> 1);             // 4..7
  size_t pbase;
  {
    int gp = p0 + sp;
    int bb = gp >> 8, ph = (gp >> 4) & 15, pwc = gp & 15;
    pbase = ((size_t)(bb * 3) * 512 + ph * 32) * 512 + pwc * 32;
  }

  f32x4 accA[4], accB[4];
#pragma unroll
  for (int i = 0; i < 4; ++i) {
    accA[i] = (f32x4){0.f, 0.f, 0.f, 0.f};
    accB[i] = (f32x4){0.f, 0.f, 0.f, 0.f};
  }

#define SLOAD(ch, R0, R1) do {                                                      \
    R0 = *(const float4*)&x[pbase + (size_t)((ch) >> 2) * 262144 +                  \
                            (size_t)(((ch) & 3) * 8 + srr0) * 512 + sj4 * 4];       \
    R1 = *(const float4*)&x[pbase + (size_t)((ch) >> 2) * 262144 +                  \
                            (size_t)(((ch) & 3) * 8 + srr1) * 512 + sj4 * 4];       \
  } while (0)

#define SPLIT4(V, HP, LP) do {                                                      \
    bf16x4 h_, lo_;                                                                 \
    h_[0] = (__bf16)V.x; lo_[0] = (__bf16)(V.x - (float)h_[0]);                     \
    h_[1] = (__bf16)V.y; lo_[1] = (__bf16)(V.y - (float)h_[1]);                     \
    h_[2] = (__bf16)V.z; lo_[2] = (__bf16)(V.z - (float)h_[2]);                     \
    h_[3] = (__bf16)V.w; lo_[3] = (__bf16)(V.w - (float)h_[3]);                     \
    *(bf16x4*)(HP) = h_; *(bf16x4*)(LP) = lo_;                                      \
  } while (0)

#define SSTORE(ch, R0, R1) do {                                                     \
    const int bf_ = (ch) & 1;                                                       \
    SPLIT4(R0, &Ah[bf_][srr0][(sj4 >> 1) * 16 + sp][(sj4 & 1) * 4],                 \
               &Al[bf_][srr0][(sj4 >> 1) * 16 + sp][(sj4 & 1) * 4]);                \
    SPLIT4(R1, &Ah[bf_][srr1][(sj4 >> 1) * 16 + sp][(sj4 & 1) * 4],                 \
               &Al[bf_][srr1][(sj4 >> 1) * 16 + sp][(sj4 & 1) * 4]);                \
  } while (0)

#define BLOAD(ch, BH, BL) do {                                                      \
    const bf16x8* wp_ = w1f + (size_t)(ch) * 4096 + wv * 64 + l;                    \
    _Pragma("unroll")                                                               \
    for (int q = 0; q < 8; ++q) { BH[q] = wp_[q * 512]; BL[q] = wp_[NFRAG + q * 512]; } \
  } while (0)

#define MFMA_PASS(ch, BH, BL) do {                                                  \
    const int bf_ = (ch) & 1;                                                       \
    _Pragma("unroll")                                                               \
    for (int ktl = 0; ktl < 8; ++ktl) {                                             \
      bf16x8 ah_ = *(const bf16x8*)&Ah[bf_][ktl][l][0];                             \
      bf16x8 al_ = *(const bf16x8*)&Al[bf_][ktl][l][0];                             \
      const int r_ = ktl & 3;                                                       \
      accA[r_] = __builtin_amdgcn_mfma_f32_16x16x32_bf16(ah_, BH[ktl], accA[r_], 0, 0, 0); \
      accB[r_] = __builtin_amdgcn_mfma_f32_16x16x32_bf16(ah_, BL[ktl], accB[r_], 0, 0, 0); \
      accB[r_] = __builtin_amdgcn_mfma_f32_16x16x32_bf16(al_, BH[ktl], accB[r_], 0, 0, 0); \
    }                                                                               \
  } while (0)

  float4 r0, r1;
  bf16x8 bh0[8], bl0[8], bh1[8], bl1[8];

  // prologue: stage chunk 0 + prefetch its B frags
  SLOAD(0, r0, r1);
  BLOAD(0, bh0, bl0);
  SSTORE(0, r0, r1);
  __syncthreads();

#pragma unroll
  for (int cc = 0; cc < 12; cc += 2) {
    if (cc + 1 < 12) { SLOAD(cc + 1, r0, r1); BLOAD(cc + 1, bh1, bl1); }
    MFMA_PASS(cc, bh0, bl0);
    if (cc + 1 < 12) SSTORE(cc + 1, r0, r1);
    __syncthreads();
    if (cc + 2 < 12) { SLOAD(cc + 2, r0, r1); BLOAD(cc + 2, bh0, bl0); }
    MFMA_PASS(cc + 1, bh1, bl1);
    if (cc + 2 < 12) SSTORE(cc + 2, r0, r1);
    __syncthreads();
  }
#undef SLOAD
#undef SPLIT4
#undef SSTORE
#undef BLOAD
#undef MFMA_PASS

  // epilogue: fixed-order reduction, bias, relu -> hs (identical to r9)
  {
    f32x4 sA = (accA[0] + accA[1]) + (accA[2] + accA[3]);
    f32x4 sB = (accB[0] + accB[1]) + (accB[2] + accB[3]);
    const int d = wv * 16 + mrow;
    const float bb1 = b1[d];
#pragma unroll
    for (int r = 0; r < 4; ++r) {
      int m = kslot * 4 + r;
      hs[m][d] = fmaxf(sA[r] + sB[r] + bb1, 0.f);
    }
  }
  __syncthreads();

  if (t < 128) {
    int p = t >> 3, e = t & 7;
    float s = 0.f;
    for (int d0 = 0; d0 < 128; d0 += 32) {
      float cs = 0.f;
#pragma unroll
      for (int dd = 0; dd < 32; ++dd)
        cs = fmaf(hs[p][d0 + dd], w2[(d0 + dd) * 8 + e], cs);
      s += cs;
    }
    ls[p][e] = s + b2[e];
  }
  __syncthreads();

  if (t < 16) {
    int gp = p0 + t;
    float v[8];
#pragma unroll
    for (int e = 0; e < 8; ++e) v[e] = ls[t][e];
    int e0 = 0;
#pragma unroll
    for (int e = 1; e < 8; ++e) if (v[e] > v[e0]) e0 = e;
    int e1 = (e0 == 0) ? 1 : 0;
#pragma unroll
    for (int e = 0; e < 8; ++e) { if (e != e0 && v[e] > v[e1]) e1 = e; }
    float bexp = expf(v[e1] - v[e0]);
    float inv  = 1.f / (1.f + bexp);
    gidx[gp * 2 + 0] = e0;
    gidx[gp * 2 + 1] = e1;
    gw[gp * 2 + 0] = inv;
    gw[gp * 2 + 1] = bexp * inv;
  }
}

// ---------------- fallback gate (r8, proven) ----------------
__global__ __launch_bounds__(512, 4) void gate_kernel(
    const float* __restrict__ x, const float* __restrict__ w1,
    const float* __restrict__ b1, const float* __restrict__ w2,
    const float* __restrict__ b2, int* __restrict__ gidx,
    float* __restrict__ gw)
{
  __shared__ float As[8][1024];
  __shared__ float hs[8][128];
  __shared__ float ls[8][8];

  const int t   = threadIdx.x;
  const int p0  = blockIdx.x * 8;
  const int d   = t & 127;
  const int grp = t >> 7;
  const int pa  = grp * 2, pb = grp * 2 + 1;

  float acc0 = 0.f, acc1 = 0.f;

  for (int c = 0; c < 3; ++c) {
#pragma unroll
    for (int it = 0; it < 4; ++it) {
      int i = t + it * 512;
      int p = i >> 8, rem = i & 255, r = rem >> 3, j4 = (rem & 7) * 4;
      int gp = p0 + p;
      int bb = gp >> 8, ph = (gp >> 4) & 15, pwc = gp & 15;
      *(float4*)&As[p][r * 32 + j4] =
          *(const float4*)&x[((size_t)(bb * 3 + c) * 512 + ph * 32 + r) * 512 + pwc * 32 + j4];
    }
    __syncthreads();

    const float* wdp = w1 + (size_t)c * 131072 + d;
    for (int ch = 0; ch < 32; ++ch) {
      float bv[32];
#pragma unroll
      for (int j = 0; j < 32; ++j) bv[j] = wdp[(ch * 32 + j) * 128];
      const int kl = ch * 32;
      float ca = 0.f, cb = 0.f;
#pragma unroll
      for (int q = 0; q < 8; ++q) {
        float4 a0 = *(const float4*)&As[pa][kl + q * 4];
        float4 a1 = *(const float4*)&As[pb][kl + q * 4];
        ca = fmaf(a0.x, bv[q * 4 + 0], ca); ca = fmaf(a0.y, bv[q * 4 + 1], ca);
        ca = fmaf(a0.z, bv[q * 4 + 2], ca); ca = fmaf(a0.w, bv[q * 4 + 3], ca);
        cb = fmaf(a1.x, bv[q * 4 + 0], cb); cb = fmaf(a1.y, bv[q * 4 + 1], cb);
        cb = fmaf(a1.z, bv[q * 4 + 2], cb); cb = fmaf(a1.w, bv[q * 4 + 3], cb);
      }
      acc0 += ca; acc1 += cb;
    }
    __syncthreads();
  }

  hs[pa][d] = fmaxf(acc0 + b1[d], 0.f);
  hs[pb][d] = fmaxf(acc1 + b1[d], 0.f);
  __syncthreads();

  if (t < 64) {
    int p = t >> 3, e = t & 7;
    float s = 0.f;
    for (int d0 = 0; d0 < 128; d0 += 32) {
      float cs = 0.f;
#pragma unroll
      for (int dd = 0; dd < 32; ++dd)
        cs = fmaf(hs[p][d0 + dd], w2[(d0 + dd) * 8 + e], cs);
      s += cs;
    }
    ls[p][e] = s + b2[e];
  }
  __syncthreads();

  if (t < 8) {
    int gp = p0 + t;
    float v[8];
#pragma unroll
    for (int e = 0; e < 8; ++e) v[e] = ls[t][e];
    int e0 = 0;
#pragma unroll
    for (int e = 1; e < 8; ++e) if (v[e] > v[e0]) e0 = e;
    int e1 = (e0 == 0) ? 1 : 0;
#pragma unroll
    for (int e = 0; e < 8; ++e) { if (e != e0 && v[e] > v[e1]) e1 = e; }
    float bexp = expf(v[e1] - v[e0]);
    float inv  = 1.f / (1.f + bexp);
    gidx[gp * 2 + 0] = e0;
    gidx[gp * 2 + 1] = e1;
    gw[gp * 2 + 0] = inv;
    gw[gp * 2 + 1] = bexp * inv;
  }
}

// ---------------- expert kernels ----------------
// Changes vs r9: dd = t&127 / half = t>>7 (y3b writes lane-contiguous = conflict-
// free; y1s reads wave-uniform broadcast; weight loads coalesced); y3b pad 140
// (afrag read conflicts 8-way -> ~3-way).

#define EXPERT_COMMON_PRE                                                          \
  __shared__ float  ps[3][32][36];                                                 \
  __shared__ float  y1s[3][256];                                                   \
  __shared__ __bf16 y3b[64][140];                                                  \
  __shared__ float  posum[4][128];                                                 \
  __shared__ float  outbuf[128];                                                   \
  const int t  = threadIdx.x;                                                      \
  const int gp = blockIdx.x;                                                       \
  const int b = gp >> 8, ph = (gp >> 4) & 15, pw = gp & 15;                        \
  const int l = t & 63, wv = t >> 6;                                               \
  _Pragma("unroll")                                                                \
  for (int it = 0; it < 3; ++it) {                                                 \
    int f4i = t + 256 * it;                                                        \
    int c = f4i >> 8, r = (f4i >> 3) & 31, j4 = f4i & 7;                           \
    *(float4*)&ps[c][r][j4 * 4] =                                                  \
        *(const float4*)&x[((size_t)(b * 3 + c) * 512 + ph * 32 + r) * 512 +       \
                           pw * 32 + j4 * 4];                                      \
  }                                                                                \
  if (t < 128) outbuf[t] = 0.f;                                                    \
  const int dd   = t & 127;                                                        \
  const int half = t >> 7;                                                         \
  __syncthreads();

#define EXPERT_PHASES_1_2                                                          \
    for (int oi = t; oi < 768; oi += 256) {                                        \
      int c = oi >> 8, p = (oi >> 4) & 15, q = oi & 15;                            \
      float a = dw1_b[e * 3 + c];                                                  \
      const float* wp_ = &dw1_w[(e * 3 + c) * 9];                                  \
      _Pragma("unroll")                                                            \
      for (int di = 0; di < 3; ++di) {                                             \
        int ii = 2 * p + di - 1;                                                   \
        if (ii < 0) continue;                                                      \
        _Pragma("unroll")                                                          \
        for (int dj = 0; dj < 3; ++dj) {                                           \
          int jj = 2 * q + dj - 1;                                                 \
          if (jj < 0) continue;                                                    \
          a = fmaf(wp_[di * 3 + dj], ps[c][ii][jj], a);                            \
        }                                                                          \
      }                                                                            \
      y1s[c][p * 16 + q] = fmaxf(a, 0.f);                                          \
    }                                                                              \
    __syncthreads();                                                               \
    {                                                                              \
      const float pwa = pw1_w[(e * 128 + dd) * 3 + 0];                             \
      const float pwb = pw1_w[(e * 128 + dd) * 3 + 1];                             \
      const float pwc = pw1_w[(e * 128 + dd) * 3 + 2];                             \
      const float pb  = pw1_b[e * 128 + dd];                                       \
      float dwv[9];                                                                \
      _Pragma("unroll")                                                            \
      for (int i = 0; i < 9; ++i) dwv[i] = dw2_w[(e * 128 + dd) * 9 + i];          \
      const float db = dw2_b[e * 128 + dd];                                        \
      for (int u = half * 4; u < half * 4 + 4; ++u) {                              \
        float vacc[8];                                                             \
        _Pragma("unroll")                                                          \
        for (int v = 0; v < 8; ++v) vacc[v] = db;                                  \
        _Pragma("unroll")                                                          \
        for (int di = 0; di < 3; ++di) {                                           \
          int ii = 2 * u + di - 1;                                                 \
          if (ii < 0) continue;                                                    \
          float y2row[16];                                                         \
          _Pragma("unroll")                                                        \
          for (int q4 = 0; q4 < 4; ++q4) {                                         \
            float4 a  = *(const float4*)&y1s[0][ii * 16 + q4 * 4];                 \
            float4 bq = *(const float4*)&y1s[1][ii * 16 + q4 * 4];                 \
            float4 cq = *(const float4*)&y1s[2][ii * 16 + q4 * 4];                 \
            y2row[q4 * 4 + 0] = fmaxf(fmaf(pwa, a.x, fmaf(pwb, bq.x, fmaf(pwc, cq.x, pb))), 0.f); \
            y2row[q4 * 4 + 1] = fmaxf(fmaf(pwa, a.y, fmaf(pwb, bq.y, fmaf(pwc, cq.y, pb))), 0.f); \
            y2row[q4 * 4 + 2] = fmaxf(fmaf(pwa, a.z, fmaf(pwb, bq.z, fmaf(pwc, cq.z, pb))), 0.f); \
            y2row[q4 * 4 + 3] = fmaxf(fmaf(pwa, a.w, fmaf(pwb, bq.w, fmaf(pwc, cq.w, pb))), 0.f); \
          }                                                                        \
          _Pragma("unroll")                                                        \
          for (int v = 0; v < 8; ++v) {                                            \
            _Pragma("unroll")                                                      \
            for (int dj = 0; dj < 3; ++dj) {                                       \
              int jj = 2 * v + dj - 1;                                             \
              if (jj < 0) continue;                                                \
              vacc[v] = fmaf(dwv[di * 3 + dj], y2row[jj], vacc[v]);                \
            }                                                                      \
          }                                                                        \
        }                                                                          \
        _Pragma("unroll")                                                          \
        for (int v = 0; v < 8; ++v)                                                \
          y3b[u * 8 + v][dd] = (__bf16)fmaxf(vacc[v], 0.f);                        \
      }                                                                            \
    }

#define EXPERT_EPILOG                                                              \
    _Pragma("unroll")                                                              \
    for (int nt = 0; nt < 8; ++nt) {                                               \
      float bias = pw2_b[e * 128 + nt * 16 + (l & 15)];                            \
      float s = fmaxf(acc[nt][0] + bias, 0.f) + fmaxf(acc[nt][1] + bias, 0.f)      \
              + fmaxf(acc[nt][2] + bias, 0.f) + fmaxf(acc[nt][3] + bias, 0.f);     \
      s += __shfl_xor(s, 16);                                                      \
      s += __shfl_xor(s, 32);                                                      \
      if (l < 16) posum[wv][nt * 16 + l] = s;                                      \
    }

__global__ __launch_bounds__(256, 4) void expert_packed(
    const float* __restrict__ x,
    const float* __restrict__ dw1_w, const float* __restrict__ dw1_b,
    const float* __restrict__ pw1_w, const float* __restrict__ pw1_b,
    const float* __restrict__ dw2_w, const float* __restrict__ dw2_b,
    const bf16x8* __restrict__ wpk, const float* __restrict__ pw2_b,
    const int* __restrict__ gidx, const float* __restrict__ gw,
    float* __restrict__ out)
{
  EXPERT_COMMON_PRE
  for (int k = 0; k < 2; ++k) {
    const int   e  = gidx[gp * 2 + k];
    const float wk = gw[gp * 2 + k];
    EXPERT_PHASES_1_2
    __syncthreads();
    {
      f32x4 acc[8];
#pragma unroll
      for (int nt = 0; nt < 8; ++nt) acc[nt] = (f32x4){0.f, 0.f, 0.f, 0.f};
      const int row  = wv * 16 + (l & 15);
      const int kofs = (l >> 4) * 8;
      bf16x8 afrag[4];
#pragma unroll
      for (int kt = 0; kt < 4; ++kt)
        afrag[kt] = *(const bf16x8*)&y3b[row][kt * 32 + kofs];
      const bf16x8* wb = wpk + (size_t)e * 2048 + l;
#pragma unroll
      for (int kt = 0; kt < 4; ++kt) {
        bf16x8 bf[8];
#pragma unroll
        for (int nt = 0; nt < 8; ++nt) bf[nt] = wb[(kt * 8 + nt) * 64];
#pragma unroll
        for (int nt = 0; nt < 8; ++nt)
          acc[nt] = __builtin_amdgcn_mfma_f32_16x16x32_bf16(afrag[kt], bf[nt], acc[nt], 0, 0, 0);
      }
      EXPERT_EPILOG
    }
    __syncthreads();
    if (t < 128)
      outbuf[t] += wk * 0.015625f *
                   (posum[0][t] + posum[1][t] + posum[2][t] + posum[3][t]);
    __syncthreads();
  }
  if (t < 128)
    out[((size_t)(b * 128 + t) * 16 + ph) * 16 + pw] = outbuf[t];
}

__global__ __launch_bounds__(256) void expert_fb(
    const float* __restrict__ x,
    const float* __restrict__ dw1_w, const float* __restrict__ dw1_b,
    const float* __restrict__ pw1_w, const float* __restrict__ pw1_b,
    const float* __restrict__ dw2_w, const float* __restrict__ dw2_b,
    const float* __restrict__ pw2_w, const float* __restrict__ pw2_b,
    const int* __restrict__ gidx, const float* __restrict__ gw,
    float* __restrict__ out)
{
  __shared__ __bf16 wlds[128][136];
  EXPERT_COMMON_PRE
  for (int k = 0; k < 2; ++k) {
    const int   e  = gidx[gp * 2 + k];
    const float wk = gw[gp * 2 + k];
    EXPERT_PHASES_1_2
    for (int i4 = t; i4 < 4096; i4 += 256) {
      int n = i4 >> 5, kq = i4 & 31;
      float4 w4 = *(const float4*)&pw2_w[((size_t)(e * 128 + n)) * 128 + kq * 4];
      bf16x4 pk = { (__bf16)w4.x, (__bf16)w4.y, (__bf16)w4.z, (__bf16)w4.w };
      *(bf16x4*)&wlds[n][kq * 4] = pk;
    }
    __syncthreads();
    {
      f32x4 acc[8];
#pragma unroll
      for (int nt = 0; nt < 8; ++nt) acc[nt] = (f32x4){0.f, 0.f, 0.f, 0.f};
      const int row  = wv * 16 + (l & 15);
      const int kofs = (l >> 4) * 8;
      bf16x8 afrag[4];
#pragma unroll
      for (int kt = 0; kt < 4; ++kt)
        afrag[kt] = *(const bf16x8*)&y3b[row][kt * 32 + kofs];
#pragma unroll
      for (int kt = 0; kt < 4; ++kt) {
#pragma unroll
        for (int nt = 0; nt < 8; ++nt) {
          bf16x8 bfrag = *(const bf16x8*)&wlds[nt * 16 + (l & 15)][kt * 32 + kofs];
          acc[nt] = __builtin_amdgcn_mfma_f32_16x16x32_bf16(afrag[kt], bfrag, acc[nt], 0, 0, 0);
        }
      }
      EXPERT_EPILOG
    }
    __syncthreads();
    if (t < 128)
      outbuf[t] += wk * 0.015625f *
                   (posum[0][t] + posum[1][t] + posum[2][t] + posum[3][t]);
    __syncthreads();
  }
  if (t < 128)
    out[((size_t)(b * 128 + t) * 16 + ph) * 16 + pw] = outbuf[t];
}

extern "C" void kernel_launch(void* const* d_in, const int* in_sizes, int n_in,
                              void* d_out, int out_size, void* d_ws, size_t ws_size,
                              hipStream_t stream) {
  const float* x       = (const float*)d_in[0];
  const float* gate_w1 = (const float*)d_in[1];
  const float* gate_b1 = (const float*)d_in[2];
  const float* gate_w2 = (const float*)d_in[3];
  const float* gate_b2 = (const float*)d_in[4];
  const float* dw1_w   = (const float*)d_in[5];
  const float* dw1_b   = (const float*)d_in[6];
  const float* pw1_w   = (const float*)d_in[7];
  const float* pw1_b   = (const float*)d_in[8];
  const float* dw2_w   = (const float*)d_in[9];
  const float* dw2_b   = (const float*)d_in[10];
  const float* pw2_w   = (const float*)d_in[11];
  const float* pw2_b   = (const float*)d_in[12];
  float* out = (float*)d_out;

  int*    gidx = (int*)d_ws;
  float*  gw   = (float*)((char*)d_ws + (size_t)NPATCH * 2 * sizeof(int));
  bf16x8* wpk  = (bf16x8*)((char*)d_ws + (size_t)NPATCH * 4 * sizeof(int));     // @64KB, 256KB
  bf16x8* w1f  = (bf16x8*)((char*)d_ws + (size_t)NPATCH * 4 * sizeof(int) + 256 * 1024);  // @320KB, 1.5MB
  const size_t ws_pack = (size_t)NPATCH * 4 * sizeof(int) + 256 * 1024;
  const size_t ws_full = ws_pack + (size_t)NFRAG * 2 * 16;
  const bool packed = ws_size >= ws_pack;
  const bool mfgate = ws_size >= ws_full;

  if (mfgate) {
    prep_w1<<<192, 256, 0, stream>>>(gate_w1, w1f);
    gate_mfma<<<NPATCH / 16, 512, 0, stream>>>(x, w1f, gate_b1, gate_w2, gate_b2, gidx, gw);
  } else {
    gate_kernel<<<NPATCH / 8, 512, 0, stream>>>(x, gate_w1, gate_b1, gate_w2, gate_b2, gidx, gw);
  }
  if (packed) {
    prep_kernel<<<64, 256, 0, stream>>>(pw2_w, wpk);
    expert_packed<<<NPATCH, 256, 0, stream>>>(x, dw1_w, dw1_b, pw1_w, pw1_b,
                                              dw2_w, dw2_b, wpk, pw2_b, gidx, gw, out);
  } else {
    expert_fb<<<NPATCH, 256, 0, stream>>>(x, dw1_w, dw1_b, pw1_w, pw1_b,
                                          dw2_w, dw2_b, pw2_w, pw2_b, gidx, gw, out);
  }
}

// Round 11
// 246.494 us; speedup vs baseline: 2.7237x; 1.0059x over previous
//
#include <hip/hip_runtime.h>

#define NPATCH 4096
#define NFRAG 49152   // 96 ktiles * 8 ntiles * 64 lanes

typedef __attribute__((ext_vector_type(8))) __bf16 bf16x8;
typedef __attribute__((ext_vector_type(4))) __bf16 bf16x4;
typedef __attribute__((ext_vector_type(4))) float f32x4;

// ---------------- prep: pack pw2 weights bf16 in MFMA fragment order ----------------
__global__ __launch_bounds__(256) void prep_kernel(const float* __restrict__ pw2_w,
                                                   bf16x8* __restrict__ wpk) {
  int tid = blockIdx.x * 256 + threadIdx.x;
  int l = tid & 63, nt = (tid >> 6) & 7, kt = (tid >> 9) & 3, e = tid >> 11;
  int n = nt * 16 + (l & 15);
  int k = kt * 32 + (l >> 4) * 8;
  const float* src = &pw2_w[((size_t)(e * 128 + n)) * 128 + k];
  float4 a = *(const float4*)src;
  float4 b = *(const float4*)(src + 4);
  bf16x8 r = { (__bf16)a.x, (__bf16)a.y, (__bf16)a.z, (__bf16)a.w,
               (__bf16)b.x, (__bf16)b.y, (__bf16)b.z, (__bf16)b.w };
  wpk[tid] = r;
}

// ---------------- prep: split gate w1 into hi/lo bf16 MFMA B-fragments ----------------
__global__ __launch_bounds__(256) void prep_w1(const float* __restrict__ w1,
                                               bf16x8* __restrict__ w1f) {
  int tid = blockIdx.x * 256 + threadIdx.x;    // 192 blocks -> 49152 threads
  int l = tid & 63, nt = (tid >> 6) & 7, ktg = tid >> 9;
  int k0 = ktg * 32 + (l >> 4) * 8, d = nt * 16 + (l & 15);
  bf16x8 h, lo;
#pragma unroll
  for (int j = 0; j < 8; ++j) {
    float v = w1[(size_t)(k0 + j) * 128 + d];
    __bf16 hv = (__bf16)v;
    h[j] = hv;
    lo[j] = (__bf16)(v - (float)hv);
  }
  w1f[tid] = h;
  w1f[NFRAG + tid] = lo;
}

// ================= shared gate-MFMA machinery (identical math to r10) =================
#define GATE_DECLS                                                                  \
  const int t  = threadIdx.x;                                                       \
  const int l  = t & 63;                                                            \
  const int wv = t >> 6;                                                            \
  const int mrow  = l & 15;                                                         \
  const int kslot = l >> 4;                                                         \
  const int sp   = l & 15;                                                          \
  const int sj4  = (l >> 4) + 4 * (wv & 1);                                         \
  const int srr0 = (wv >> 1);                                                       \
  const int srr1 = 4 + (wv >> 1);

#define SLOAD(ch, R0, R1) do {                                                      \
    R0 = *(const float4*)&x[pbase + (size_t)((ch) >> 2) * 262144 +                  \
                            (size_t)(((ch) & 3) * 8 + srr0) * 512 + sj4 * 4];       \
    R1 = *(const float4*)&x[pbase + (size_t)((ch) >> 2) * 262144 +                  \
                            (size_t)(((ch) & 3) * 8 + srr1) * 512 + sj4 * 4];       \
  } while (0)

#define SPLIT4(V, HP, LP) do {                                                      \
    bf16x4 h_, lo_;                                                                 \
    h_[0] = (__bf16)V.x; lo_[0] = (__bf16)(V.x - (float)h_[0]);                     \
    h_[1] = (__bf16)V.y; lo_[1] = (__bf16)(V.y - (float)h_[1]);                     \
    h_[2] = (__bf16)V.z; lo_[2] = (__bf16)(V.z - (float)h_[2]);                     \
    h_[3] = (__bf16)V.w; lo_[3] = (__bf16)(V.w - (float)h_[3]);                     \
    *(bf16x4*)(HP) = h_; *(bf16x4*)(LP) = lo_;                                      \
  } while (0)

#define SSTORE(ch, R0, R1) do {                                                     \
    const int bf_ = (ch) & 1;                                                       \
    SPLIT4(R0, &Ah[bf_][srr0][(sj4 >> 1) * 16 + sp][(sj4 & 1) * 4],                 \
               &Al[bf_][srr0][(sj4 >> 1) * 16 + sp][(sj4 & 1) * 4]);                \
    SPLIT4(R1, &Ah[bf_][srr1][(sj4 >> 1) * 16 + sp][(sj4 & 1) * 4],                 \
               &Al[bf_][srr1][(sj4 >> 1) * 16 + sp][(sj4 & 1) * 4]);                \
  } while (0)

#define BLOAD(ch, BH, BL) do {                                                      \
    const bf16x8* wp_ = w1f + (size_t)(ch) * 4096 + wv * 64 + l;                    \
    _Pragma("unroll")                                                               \
    for (int q = 0; q < 8; ++q) { BH[q] = wp_[q * 512]; BL[q] = wp_[NFRAG + q * 512]; } \
  } while (0)

#define MFMA_PASS(ch, BH, BL) do {                                                  \
    const int bf_ = (ch) & 1;                                                       \
    _Pragma("unroll")                                                               \
    for (int ktl = 0; ktl < 8; ++ktl) {                                             \
      bf16x8 ah_ = *(const bf16x8*)&Ah[bf_][ktl][l][0];                             \
      bf16x8 al_ = *(const bf16x8*)&Al[bf_][ktl][l][0];                             \
      const int r_ = ktl & 3;                                                       \
      accA[r_] = __builtin_amdgcn_mfma_f32_16x16x32_bf16(ah_, BH[ktl], accA[r_], 0, 0, 0); \
      accB[r_] = __builtin_amdgcn_mfma_f32_16x16x32_bf16(ah_, BL[ktl], accB[r_], 0, 0, 0); \
      accB[r_] = __builtin_amdgcn_mfma_f32_16x16x32_bf16(al_, BH[ktl], accB[r_], 0, 0, 0); \
    }                                                                               \
  } while (0)

// ---------------- split-K gate: 512 blocks x 512 threads ----------------
// block = (16 patches) x (K-half of 6 chunks); partials -> hpart[2][4096][128].
// 2 blocks/CU -> 16 waves/CU (vs 8 in r10's full-K version).
__global__ __launch_bounds__(512) void gate_mfma_split(
    const float* __restrict__ x, const bf16x8* __restrict__ w1f,
    float* __restrict__ hpart)
{
  __shared__ __bf16 Ah[2][8][64][8];   // 16 KB
  __shared__ __bf16 Al[2][8][64][8];   // 16 KB

  GATE_DECLS
  const int kh = blockIdx.x & 1;
  const int p0 = (blockIdx.x >> 1) * 16;
  const int cb = kh * 6;

  size_t pbase;
  {
    int gp = p0 + sp;
    int bb = gp >> 8, ph = (gp >> 4) & 15, pwc = gp & 15;
    pbase = ((size_t)(bb * 3) * 512 + ph * 32) * 512 + pwc * 32;
  }

  f32x4 accA[4], accB[4];
#pragma unroll
  for (int i = 0; i < 4; ++i) {
    accA[i] = (f32x4){0.f, 0.f, 0.f, 0.f};
    accB[i] = (f32x4){0.f, 0.f, 0.f, 0.f};
  }

  float4 r0, r1;
  bf16x8 bh0[8], bl0[8], bh1[8], bl1[8];

  SLOAD(cb + 0, r0, r1);
  BLOAD(cb + 0, bh0, bl0);
  SSTORE(cb + 0, r0, r1);
  __syncthreads();

#pragma unroll
  for (int cc = 0; cc < 6; cc += 2) {
    if (cc + 1 < 6) { SLOAD(cb + cc + 1, r0, r1); BLOAD(cb + cc + 1, bh1, bl1); }
    MFMA_PASS(cb + cc, bh0, bl0);
    if (cc + 1 < 6) SSTORE(cb + cc + 1, r0, r1);
    __syncthreads();
    if (cc + 2 < 6) { SLOAD(cb + cc + 2, r0, r1); BLOAD(cb + cc + 2, bh0, bl0); }
    MFMA_PASS(cb + cc + 1, bh1, bl1);
    if (cc + 2 < 6) SSTORE(cb + cc + 2, r0, r1);
    __syncthreads();
  }

  // partial sums (fixed-order reduction, no bias/relu)
  {
    f32x4 sA = (accA[0] + accA[1]) + (accA[2] + accA[3]);
    f32x4 sB = (accB[0] + accB[1]) + (accB[2] + accB[3]);
    const int d = wv * 16 + mrow;
#pragma unroll
    for (int r = 0; r < 4; ++r) {
      int m = kslot * 4 + r;
      hpart[((size_t)kh * NPATCH + p0 + m) * 128 + d] = sA[r] + sB[r];
    }
  }
}

// ---------------- gate logits+top2 from split partials ----------------
__global__ __launch_bounds__(256) void gate_logits(
    const float* __restrict__ hpart, const float* __restrict__ b1,
    const float* __restrict__ w2, const float* __restrict__ b2,
    int* __restrict__ gidx, float* __restrict__ gw)
{
  __shared__ float hs[16][128];
  __shared__ float ls[16][8];
  const int t  = threadIdx.x;
  const int p0 = blockIdx.x * 16;

  for (int i = t; i < 2048; i += 256) {
    int p = i >> 7, d = i & 127;
    float h0 = hpart[((size_t)(p0 + p)) * 128 + d];
    float h1 = hpart[((size_t)NPATCH + p0 + p) * 128 + d];
    hs[p][d] = fmaxf((h0 + h1) + b1[d], 0.f);
  }
  __syncthreads();

  if (t < 128) {
    int p = t >> 3, e = t & 7;
    float s = 0.f;
    for (int d0 = 0; d0 < 128; d0 += 32) {
      float cs = 0.f;
#pragma unroll
      for (int dd = 0; dd < 32; ++dd)
        cs = fmaf(hs[p][d0 + dd], w2[(d0 + dd) * 8 + e], cs);
      s += cs;
    }
    ls[p][e] = s + b2[e];
  }
  __syncthreads();

  if (t < 16) {
    int gp = p0 + t;
    float v[8];
#pragma unroll
    for (int e = 0; e < 8; ++e) v[e] = ls[t][e];
    int e0 = 0;
#pragma unroll
    for (int e = 1; e < 8; ++e) if (v[e] > v[e0]) e0 = e;
    int e1 = (e0 == 0) ? 1 : 0;
#pragma unroll
    for (int e = 0; e < 8; ++e) { if (e != e0 && v[e] > v[e1]) e1 = e; }
    float bexp = expf(v[e1] - v[e0]);
    float inv  = 1.f / (1.f + bexp);
    gidx[gp * 2 + 0] = e0;
    gidx[gp * 2 + 1] = e1;
    gw[gp * 2 + 0] = inv;
    gw[gp * 2 + 1] = bexp * inv;
  }
}

// ---------------- full-K gate (r10, proven fallback) ----------------
__global__ __launch_bounds__(512) void gate_mfma(
    const float* __restrict__ x, const bf16x8* __restrict__ w1f,
    const float* __restrict__ b1, const float* __restrict__ w2,
    const float* __restrict__ b2, int* __restrict__ gidx,
    float* __restrict__ gw)
{
  __shared__ __bf16 Ah[2][8][64][8];
  __shared__ __bf16 Al[2][8][64][8];
  __shared__ float hs[16][128];
  __shared__ float ls[16][8];

  GATE_DECLS
  const int p0 = blockIdx.x * 16;

  size_t pbase;
  {
    int gp = p0 + sp;
    int bb = gp >> 8, ph = (gp >> 4) & 15, pwc = gp & 15;
    pbase = ((size_t)(bb * 3) * 512 + ph * 32) * 512 + pwc * 32;
  }

  f32x4 accA[4], accB[4];
#pragma unroll
  for (int i = 0; i < 4; ++i) {
    accA[i] = (f32x4){0.f, 0.f, 0.f, 0.f};
    accB[i] = (f32x4){0.f, 0.f, 0.f, 0.f};
  }

  float4 r0, r1;
  bf16x8 bh0[8], bl0[8], bh1[8], bl1[8];

  SLOAD(0, r0, r1);
  BLOAD(0, bh0, bl0);
  SSTORE(0, r0, r1);
  __syncthreads();

#pragma unroll
  for (int cc = 0; cc < 12; cc += 2) {
    if (cc + 1 < 12) { SLOAD(cc + 1, r0, r1); BLOAD(cc + 1, bh1, bl1); }
    MFMA_PASS(cc, bh0, bl0);
    if (cc + 1 < 12) SSTORE(cc + 1, r0, r1);
    __syncthreads();
    if (cc + 2 < 12) { SLOAD(cc + 2, r0, r1); BLOAD(cc + 2, bh0, bl0); }
    MFMA_PASS(cc + 1, bh1, bl1);
    if (cc + 2 < 12) SSTORE(cc + 2, r0, r1);
    __syncthreads();
  }

  {
    f32x4 sA = (accA[0] + accA[1]) + (accA[2] + accA[3]);
    f32x4 sB = (accB[0] + accB[1]) + (accB[2] + accB[3]);
    const int d = wv * 16 + mrow;
    const float bb1 = b1[d];
#pragma unroll
    for (int r = 0; r < 4; ++r) {
      int m = kslot * 4 + r;
      hs[m][d] = fmaxf(sA[r] + sB[r] + bb1, 0.f);
    }
  }
  __syncthreads();

  if (t < 128) {
    int p = t >> 3, e = t & 7;
    float s = 0.f;
    for (int d0 = 0; d0 < 128; d0 += 32) {
      float cs = 0.f;
#pragma unroll
      for (int dd = 0; dd < 32; ++dd)
        cs = fmaf(hs[p][d0 + dd], w2[(d0 + dd) * 8 + e], cs);
      s += cs;
    }
    ls[p][e] = s + b2[e];
  }
  __syncthreads();

  if (t < 16) {
    int gp = p0 + t;
    float v[8];
#pragma unroll
    for (int e = 0; e < 8; ++e) v[e] = ls[t][e];
    int e0 = 0;
#pragma unroll
    for (int e = 1; e < 8; ++e) if (v[e] > v[e0]) e0 = e;
    int e1 = (e0 == 0) ? 1 : 0;
#pragma unroll
    for (int e = 0; e < 8; ++e) { if (e != e0 && v[e] > v[e1]) e1 = e; }
    float bexp = expf(v[e1] - v[e0]);
    float inv  = 1.f / (1.f + bexp);
    gidx[gp * 2 + 0] = e0;
    gidx[gp * 2 + 1] = e1;
    gw[gp * 2 + 0] = inv;
    gw[gp * 2 + 1] = bexp * inv;
  }
}

// ---------------- fallback gate (r8, proven) ----------------
__global__ __launch_bounds__(512, 4) void gate_kernel(
    const float* __restrict__ x, const float* __restrict__ w1,
    const float* __restrict__ b1, const float* __restrict__ w2,
    const float* __restrict__ b2, int* __restrict__ gidx,
    float* __restrict__ gw)
{
  __shared__ float As[8][1024];
  __shared__ float hs[8][128];
  __shared__ float ls[8][8];

  const int t   = threadIdx.x;
  const int p0  = blockIdx.x * 8;
  const int d   = t & 127;
  const int grp = t >> 7;
  const int pa  = grp * 2, pb = grp * 2 + 1;

  float acc0 = 0.f, acc1 = 0.f;

  for (int c = 0; c < 3; ++c) {
#pragma unroll
    for (int it = 0; it < 4; ++it) {
      int i = t + it * 512;
      int p = i >> 8, rem = i & 255, r = rem >> 3, j4 = (rem & 7) * 4;
      int gp = p0 + p;
      int bb = gp >> 8, ph = (gp >> 4) & 15, pwc = gp & 15;
      *(float4*)&As[p][r * 32 + j4] =
          *(const float4*)&x[((size_t)(bb * 3 + c) * 512 + ph * 32 + r) * 512 + pwc * 32 + j4];
    }
    __syncthreads();

    const float* wdp = w1 + (size_t)c * 131072 + d;
    for (int ch = 0; ch < 32; ++ch) {
      float bv[32];
#pragma unroll
      for (int j = 0; j < 32; ++j) bv[j] = wdp[(ch * 32 + j) * 128];
      const int kl = ch * 32;
      float ca = 0.f, cb = 0.f;
#pragma unroll
      for (int q = 0; q < 8; ++q) {
        float4 a0 = *(const float4*)&As[pa][kl + q * 4];
        float4 a1 = *(const float4*)&As[pb][kl + q * 4];
        ca = fmaf(a0.x, bv[q * 4 + 0], ca); ca = fmaf(a0.y, bv[q * 4 + 1], ca);
        ca = fmaf(a0.z, bv[q * 4 + 2], ca); ca = fmaf(a0.w, bv[q * 4 + 3], ca);
        cb = fmaf(a1.x, bv[q * 4 + 0], cb); cb = fmaf(a1.y, bv[q * 4 + 1], cb);
        cb = fmaf(a1.z, bv[q * 4 + 2], cb); cb = fmaf(a1.w, bv[q * 4 + 3], cb);
      }
      acc0 += ca; acc1 += cb;
    }
    __syncthreads();
  }

  hs[pa][d] = fmaxf(acc0 + b1[d], 0.f);
  hs[pb][d] = fmaxf(acc1 + b1[d], 0.f);
  __syncthreads();

  if (t < 64) {
    int p = t >> 3, e = t & 7;
    float s = 0.f;
    for (int d0 = 0; d0 < 128; d0 += 32) {
      float cs = 0.f;
#pragma unroll
      for (int dd = 0; dd < 32; ++dd)
        cs = fmaf(hs[p][d0 + dd], w2[(d0 + dd) * 8 + e], cs);
      s += cs;
    }
    ls[p][e] = s + b2[e];
  }
  __syncthreads();

  if (t < 8) {
    int gp = p0 + t;
    float v[8];
#pragma unroll
    for (int e = 0; e < 8; ++e) v[e] = ls[t][e];
    int e0 = 0;
#pragma unroll
    for (int e = 1; e < 8; ++e) if (v[e] > v[e0]) e0 = e;
    int e1 = (e0 == 0) ? 1 : 0;
#pragma unroll
    for (int e = 0; e < 8; ++e) { if (e != e0 && v[e] > v[e1]) e1 = e; }
    float bexp = expf(v[e1] - v[e0]);
    float inv  = 1.f / (1.f + bexp);
    gidx[gp * 2 + 0] = e0;
    gidx[gp * 2 + 1] = e1;
    gw[gp * 2 + 0] = inv;
    gw[gp * 2 + 1] = bexp * inv;
  }
}

// ---------------- expert kernels (unchanged from r10) ----------------
#define EXPERT_COMMON_PRE                                                          \
  __shared__ float  ps[3][32][36];                                                 \
  __shared__ float  y1s[3][256];                                                   \
  __shared__ __bf16 y3b[64][140];                                                  \
  __shared__ float  posum[4][128];                                                 \
  __shared__ float  outbuf[128];                                                   \
  const int t  = threadIdx.x;                                                      \
  const int gp = blockIdx.x;                                                       \
  const int b = gp >> 8, ph = (gp >> 4) & 15, pw = gp & 15;                        \
  const int l = t & 63, wv = t >> 6;                                               \
  _Pragma("unroll")                                                                \
  for (int it = 0; it < 3; ++it) {                                                 \
    int f4i = t + 256 * it;                                                        \
    int c = f4i >> 8, r = (f4i >> 3) & 31, j4 = f4i & 7;                           \
    *(float4*)&ps[c][r][j4 * 4] =                                                  \
        *(const float4*)&x[((size_t)(b * 3 + c) * 512 + ph * 32 + r) * 512 +       \
                           pw * 32 + j4 * 4];                                      \
  }                                                                                \
  if (t < 128) outbuf[t] = 0.f;                                                    \
  const int dd   = t & 127;                                                        \
  const int half = t >> 7;                                                         \
  __syncthreads();

#define EXPERT_PHASES_1_2                                                          \
    for (int oi = t; oi < 768; oi += 256) {                                        \
      int c = oi >> 8, p = (oi >> 4) & 15, q = oi & 15;                            \
      float a = dw1_b[e * 3 + c];                                                  \
      const float* wp_ = &dw1_w[(e * 3 + c) * 9];                                  \
      _Pragma("unroll")                                                            \
      for (int di = 0; di < 3; ++di) {                                             \
        int ii = 2 * p + di - 1;                                                   \
        if (ii < 0) continue;                                                      \
        _Pragma("unroll")                                                          \
        for (int dj = 0; dj < 3; ++dj) {                                           \
          int jj = 2 * q + dj - 1;                                                 \
          if (jj < 0) continue;                                                    \
          a = fmaf(wp_[di * 3 + dj], ps[c][ii][jj], a);                            \
        }                                                                          \
      }                                                                            \
      y1s[c][p * 16 + q] = fmaxf(a, 0.f);                                          \
    }                                                                              \
    __syncthreads();                                                               \
    {                                                                              \
      const float pwa = pw1_w[(e * 128 + dd) * 3 + 0];                             \
      const float pwb = pw1_w[(e * 128 + dd) * 3 + 1];                             \
      const float pwc = pw1_w[(e * 128 + dd) * 3 + 2];                             \
      const float pb  = pw1_b[e * 128 + dd];                                       \
      float dwv[9];                                                                \
      _Pragma("unroll")                                                            \
      for (int i = 0; i < 9; ++i) dwv[i] = dw2_w[(e * 128 + dd) * 9 + i];          \
      const float db = dw2_b[e * 128 + dd];                                        \
      for (int u = half * 4; u < half * 4 + 4; ++u) {                              \
        float vacc[8];                                                             \
        _Pragma("unroll")                                                          \
        for (int v = 0; v < 8; ++v) vacc[v] = db;                                  \
        _Pragma("unroll")                                                          \
        for (int di = 0; di < 3; ++di) {                                           \
          int ii = 2 * u + di - 1;                                                 \
          if (ii < 0) continue;                                                    \
          float y2row[16];                                                         \
          _Pragma("unroll")                                                        \
          for (int q4 = 0; q4 < 4; ++q4) {                                         \
            float4 a  = *(const float4*)&y1s[0][ii * 16 + q4 * 4];                 \
            float4 bq = *(const float4*)&y1s[1][ii * 16 + q4 * 4];                 \
            float4 cq = *(const float4*)&y1s[2][ii * 16 + q4 * 4];                 \
            y2row[q4 * 4 + 0] = fmaxf(fmaf(pwa, a.x, fmaf(pwb, bq.x, fmaf(pwc, cq.x, pb))), 0.f); \
            y2row[q4 * 4 + 1] = fmaxf(fmaf(pwa, a.y, fmaf(pwb, bq.y, fmaf(pwc, cq.y, pb))), 0.f); \
            y2row[q4 * 4 + 2] = fmaxf(fmaf(pwa, a.z, fmaf(pwb, bq.z, fmaf(pwc, cq.z, pb))), 0.f); \
            y2row[q4 * 4 + 3] = fmaxf(fmaf(pwa, a.w, fmaf(pwb, bq.w, fmaf(pwc, cq.w, pb))), 0.f); \
          }                                                                        \
          _Pragma("unroll")                                                        \
          for (int v = 0; v < 8; ++v) {                                            \
            _Pragma("unroll")                                                      \
            for (int dj = 0; dj < 3; ++dj) {                                       \
              int jj = 2 * v + dj - 1;                                             \
              if (jj < 0) continue;                                                \
              vacc[v] = fmaf(dwv[di * 3 + dj], y2row[jj], vacc[v]);                \
            }                                                                      \
          }                                                                        \
        }                                                                          \
        _Pragma("unroll")                                                          \
        for (int v = 0; v < 8; ++v)                                                \
          y3b[u * 8 + v][dd] = (__bf16)fmaxf(vacc[v], 0.f);                        \
      }                                                                            \
    }

#define EXPERT_EPILOG                                                              \
    _Pragma("unroll")                                                              \
    for (int nt = 0; nt < 8; ++nt) {                                               \
      float bias = pw2_b[e * 128 + nt * 16 + (l & 15)];                            \
      float s = fmaxf(acc[nt][0] + bias, 0.f) + fmaxf(acc[nt][1] + bias, 0.f)      \
              + fmaxf(acc[nt][2] + bias, 0.f) + fmaxf(acc[nt][3] + bias, 0.f);     \
      s += __shfl_xor(s, 16);                                                      \
      s += __shfl_xor(s, 32);                                                      \
      if (l < 16) posum[wv][nt * 16 + l] = s;                                      \
    }

__global__ __launch_bounds__(256, 4) void expert_packed(
    const float* __restrict__ x,
    const float* __restrict__ dw1_w, const float* __restrict__ dw1_b,
    const float* __restrict__ pw1_w, const float* __restrict__ pw1_b,
    const float* __restrict__ dw2_w, const float* __restrict__ dw2_b,
    const bf16x8* __restrict__ wpk, const float* __restrict__ pw2_b,
    const int* __restrict__ gidx, const float* __restrict__ gw,
    float* __restrict__ out)
{
  EXPERT_COMMON_PRE
  for (int k = 0; k < 2; ++k) {
    const int   e  = gidx[gp * 2 + k];
    const float wk = gw[gp * 2 + k];
    EXPERT_PHASES_1_2
    __syncthreads();
    {
      f32x4 acc[8];
#pragma unroll
      for (int nt = 0; nt < 8; ++nt) acc[nt] = (f32x4){0.f, 0.f, 0.f, 0.f};
      const int row  = wv * 16 + (l & 15);
      const int kofs = (l >> 4) * 8;
      bf16x8 afrag[4];
#pragma unroll
      for (int kt = 0; kt < 4; ++kt)
        afrag[kt] = *(const bf16x8*)&y3b[row][kt * 32 + kofs];
      const bf16x8* wb = wpk + (size_t)e * 2048 + l;
#pragma unroll
      for (int kt = 0; kt < 4; ++kt) {
        bf16x8 bf[8];
#pragma unroll
        for (int nt = 0; nt < 8; ++nt) bf[nt] = wb[(kt * 8 + nt) * 64];
#pragma unroll
        for (int nt = 0; nt < 8; ++nt)
          acc[nt] = __builtin_amdgcn_mfma_f32_16x16x32_bf16(afrag[kt], bf[nt], acc[nt], 0, 0, 0);
      }
      EXPERT_EPILOG
    }
    __syncthreads();
    if (t < 128)
      outbuf[t] += wk * 0.015625f *
                   (posum[0][t] + posum[1][t] + posum[2][t] + posum[3][t]);
    __syncthreads();
  }
  if (t < 128)
    out[((size_t)(b * 128 + t) * 16 + ph) * 16 + pw] = outbuf[t];
}

__global__ __launch_bounds__(256) void expert_fb(
    const float* __restrict__ x,
    const float* __restrict__ dw1_w, const float* __restrict__ dw1_b,
    const float* __restrict__ pw1_w, const float* __restrict__ pw1_b,
    const float* __restrict__ dw2_w, const float* __restrict__ dw2_b,
    const float* __restrict__ pw2_w, const float* __restrict__ pw2_b,
    const int* __restrict__ gidx, const float* __restrict__ gw,
    float* __restrict__ out)
{
  __shared__ __bf16 wlds[128][136];
  EXPERT_COMMON_PRE
  for (int k = 0; k < 2; ++k) {
    const int   e  = gidx[gp * 2 + k];
    const float wk = gw[gp * 2 + k];
    EXPERT_PHASES_1_2
    for (int i4 = t; i4 < 4096; i4 += 256) {
      int n = i4 >> 5, kq = i4 & 31;
      float4 w4 = *(const float4*)&pw2_w[((size_t)(e * 128 + n)) * 128 + kq * 4];
      bf16x4 pk = { (__bf16)w4.x, (__bf16)w4.y, (__bf16)w4.z, (__bf16)w4.w };
      *(bf16x4*)&wlds[n][kq * 4] = pk;
    }
    __syncthreads();
    {
      f32x4 acc[8];
#pragma unroll
      for (int nt = 0; nt < 8; ++nt) acc[nt] = (f32x4){0.f, 0.f, 0.f, 0.f};
      const int row  = wv * 16 + (l & 15);
      const int kofs = (l >> 4) * 8;
      bf16x8 afrag[4];
#pragma unroll
      for (int kt = 0; kt < 4; ++kt)
        afrag[kt] = *(const bf16x8*)&y3b[row][kt * 32 + kofs];
#pragma unroll
      for (int kt = 0; kt < 4; ++kt) {
#pragma unroll
        for (int nt = 0; nt < 8; ++nt) {
          bf16x8 bfrag = *(const bf16x8*)&wlds[nt * 16 + (l & 15)][kt * 32 + kofs];
          acc[nt] = __builtin_amdgcn_mfma_f32_16x16x32_bf16(afrag[kt], bfrag, acc[nt], 0, 0, 0);
        }
      }
      EXPERT_EPILOG
    }
    __syncthreads();
    if (t < 128)
      outbuf[t] += wk * 0.015625f *
                   (posum[0][t] + posum[1][t] + posum[2][t] + posum[3][t]);
    __syncthreads();
  }
  if (t < 128)
    out[((size_t)(b * 128 + t) * 16 + ph) * 16 + pw] = outbuf[t];
}

extern "C" void kernel_launch(void* const* d_in, const int* in_sizes, int n_in,
                              void* d_out, int out_size, void* d_ws, size_t ws_size,
                              hipStream_t stream) {
  const float* x       = (const float*)d_in[0];
  const float* gate_w1 = (const float*)d_in[1];
  const float* gate_b1 = (const float*)d_in[2];
  const float* gate_w2 = (const float*)d_in[3];
  const float* gate_b2 = (const float*)d_in[4];
  const float* dw1_w   = (const float*)d_in[5];
  const float* dw1_b   = (const float*)d_in[6];
  const float* pw1_w   = (const float*)d_in[7];
  const float* pw1_b   = (const float*)d_in[8];
  const float* dw2_w   = (const float*)d_in[9];
  const float* dw2_b   = (const float*)d_in[10];
  const float* pw2_w   = (const float*)d_in[11];
  const float* pw2_b   = (const float*)d_in[12];
  float* out = (float*)d_out;

  const size_t off_wpk   = (size_t)NPATCH * 4 * sizeof(int);      // 64 KB
  const size_t off_w1f   = off_wpk + 256 * 1024;                  // 320 KB
  const size_t off_hpart = off_w1f + (size_t)NFRAG * 2 * 16;      // ~1.86 MB
  const size_t ws_pack   = off_w1f;
  const size_t ws_full   = off_hpart;
  const size_t ws_split  = off_hpart + (size_t)2 * NPATCH * 128 * sizeof(float);  // ~5.9 MB

  int*    gidx  = (int*)d_ws;
  float*  gw    = (float*)((char*)d_ws + (size_t)NPATCH * 2 * sizeof(int));
  bf16x8* wpk   = (bf16x8*)((char*)d_ws + off_wpk);
  bf16x8* w1f   = (bf16x8*)((char*)d_ws + off_w1f);
  float*  hpart = (float*)((char*)d_ws + off_hpart);

  const bool packed  = ws_size >= ws_pack;
  const bool mfgate  = ws_size >= ws_full;
  const bool splitk  = ws_size >= ws_split;

  if (splitk) {
    prep_w1<<<192, 256, 0, stream>>>(gate_w1, w1f);
    gate_mfma_split<<<512, 512, 0, stream>>>(x, w1f, hpart);
    gate_logits<<<NPATCH / 16, 256, 0, stream>>>(hpart, gate_b1, gate_w2, gate_b2, gidx, gw);
  } else if (mfgate) {
    prep_w1<<<192, 256, 0, stream>>>(gate_w1, w1f);
    gate_mfma<<<NPATCH / 16, 512, 0, stream>>>(x, w1f, gate_b1, gate_w2, gate_b2, gidx, gw);
  } else {
    gate_kernel<<<NPATCH / 8, 512, 0, stream>>>(x, gate_w1, gate_b1, gate_w2, gate_b2, gidx, gw);
  }
  if (packed) {
    prep_kernel<<<64, 256, 0, stream>>>(pw2_w, wpk);
    expert_packed<<<NPATCH, 256, 0, stream>>>(x, dw1_w, dw1_b, pw1_w, pw1_b,
                                              dw2_w, dw2_b, wpk, pw2_b, gidx, gw, out);
  } else {
    expert_fb<<<NPATCH, 256, 0, stream>>>(x, dw1_w, dw1_b, pw1_w, pw1_b,
                                          dw2_w, dw2_b, pw2_w, pw2_b, gidx, gw, out);
  }
}